// Round 17
// baseline (728.709 us; speedup 1.0000x reference)
//
#include <hip/hip_runtime.h>
#include <math.h>

typedef unsigned short u16;
typedef _Float16 f16;
typedef __attribute__((ext_vector_type(8))) _Float16 f16x8;
typedef __attribute__((ext_vector_type(4))) float f32x4;
typedef __attribute__((ext_vector_type(8))) unsigned short u16x8;

constexpr int NN   = 20000;
constexpr int EE   = 320000;
constexpr int CD   = 256;
constexpr int IND  = 128;
constexpr int OUTD = 128;
constexpr int LL   = 3;
constexpr int GG   = 16;
constexpr float EPSV = 1e-5f;

__device__ __forceinline__ u16 f2h(float f) {
    union { f16 h; u16 u; } v; v.h = (f16)f; return v.u;
}
__device__ __forceinline__ float h2f(u16 u) {
    union { u16 u; f16 h; } v; v.u = u; return (float)v.h;
}

// ---------------------------------------------------------------------------
// CSR build: fused edge histogram + batch histogram
// ---------------------------------------------------------------------------
__global__ void hist_kernel(const int* __restrict__ dst, const int* __restrict__ batch,
                            int* __restrict__ counts, int* __restrict__ cntg) {
    __shared__ int loc[GG];
    if (threadIdx.x < GG) loc[threadIdx.x] = 0;
    __syncthreads();
    int stride = gridDim.x * blockDim.x;
    for (int e = blockIdx.x * blockDim.x + threadIdx.x; e < EE; e += stride)
        atomicAdd(&counts[dst[e]], 1);
    for (int i = blockIdx.x * blockDim.x + threadIdx.x; i < NN; i += stride)
        atomicAdd(&loc[batch[i]], 1);
    __syncthreads();
    if (threadIdx.x < GG) atomicAdd(&cntg[threadIdx.x], loc[threadIdx.x]);
}

__global__ __launch_bounds__(1024) void scan_kernel(const int* __restrict__ counts,
                                                    int* __restrict__ offsets,
                                                    float* __restrict__ dinv) {
    __shared__ int ls[1024];
    int t = threadIdx.x;
    const int CHK = (NN + 1023) / 1024;
    int begin = t * CHK;
    int end   = begin + CHK; if (end > NN) end = NN;
    int s = 0;
    for (int i = begin; i < end && i < NN; ++i) s += counts[i];
    ls[t] = s;
    __syncthreads();
    for (int off = 1; off < 1024; off <<= 1) {
        int v = (t >= off) ? ls[t - off] : 0;
        __syncthreads();
        ls[t] += v;
        __syncthreads();
    }
    int run = ls[t] - s;
    for (int i = begin; i < end && i < NN; ++i) {
        offsets[i] = run;
        int c = counts[i];
        run += c;
        dinv[i] = rsqrtf((float)(c + 1));
    }
    if (t == 1023) offsets[NN] = run;
}

__global__ void fill_kernel(const int* __restrict__ src, const int* __restrict__ dst,
                            const int* __restrict__ offsets, int* __restrict__ cursor,
                            const float* __restrict__ dinv,
                            int* __restrict__ srcs, float* __restrict__ wts) {
    int e = blockIdx.x * blockDim.x + threadIdx.x;
    if (e >= EE) return;
    int d = dst[e];
    int p = atomicAdd(&cursor[d], 1);
    int pos = offsets[d] + p;
    int s = src[e];
    srcs[pos] = s;
    wts[pos]  = dinv[s];
}

// ---------------------------------------------------------------------------
// Fused f32 -> f16 conversion of x + all weights (one launch)
// ---------------------------------------------------------------------------
__global__ void conv_all_kernel(const float* __restrict__ x,   const float* __restrict__ gcn_w,
                                const float* __restrict__ ggc, const float* __restrict__ wih,
                                const float* __restrict__ whh, const float* __restrict__ lin,
                                u16* __restrict__ x_h,  u16* __restrict__ gcn_h,
                                u16* __restrict__ ggc_h, u16* __restrict__ wih_h,
                                u16* __restrict__ whh_h, u16* __restrict__ lin_h) {
    const int b0 = NN * IND / 4;
    const int b1 = b0 + CD * IND / 4;
    const int b2 = b1 + 6 * CD * CD / 4;
    const int b3 = b2 + LL * 3 * CD * CD / 4;
    const int b4 = b3 + LL * 3 * CD * CD / 4;
    const int b5 = b4 + OUTD * CD / 4;
    int i = blockIdx.x * blockDim.x + threadIdx.x;
    if (i >= b5) return;
    const float* src; u16* dst; int base;
    if (i < b0)      { src = x;     dst = x_h;   base = 0;  }
    else if (i < b1) { src = gcn_w; dst = gcn_h; base = b0; }
    else if (i < b2) { src = ggc;   dst = ggc_h; base = b1; }
    else if (i < b3) { src = wih;   dst = wih_h; base = b2; }
    else if (i < b4) { src = whh;   dst = whh_h; base = b3; }
    else             { src = lin;   dst = lin_h; base = b4; }
    int j = i - base;
    float4 v = ((const float4*)src)[j];
    ushort4 o;
    o.x = f2h(v.x); o.y = f2h(v.y); o.z = f2h(v.z); o.w = f2h(v.w);
    ((ushort4*)dst)[j] = o;
}

// ---------------------------------------------------------------------------
// f16 MFMA GEMM tile body: C[M,N] = A[M,K] * B^T (B stored [N,K]) (+bias)
// 128x128 tile, BK=64, 4 waves, global_load_lds w16, XOR-swizzled LDS (T2).
// STATS: also accumulate per-(graph,col) sums/sumsq of the f32 outputs.
// ---------------------------------------------------------------------------
template<bool BIAS, bool OUTH, bool STATS>
__device__ __forceinline__ void gemm_tile(const u16* __restrict__ A,
                                          const u16* __restrict__ B,
                                          const float* __restrict__ bias,
                                          float* __restrict__ Cf,
                                          u16* __restrict__ Ch,
                                          int M, int N, int K,
                                          int bm, int bn,
                                          u16* As, u16* Bs,
                                          const int* __restrict__ batch,
                                          float* __restrict__ sums,
                                          float* __restrict__ sumsq) {
    const int tid  = threadIdx.x;
    const int lane = tid & 63;
    const int wave = tid >> 6;
    const int wr = wave >> 1, wc = wave & 1;

    f32x4 acc[4][4];
    #pragma unroll
    for (int i = 0; i < 4; ++i)
        #pragma unroll
        for (int j = 0; j < 4; ++j) acc[i][j] = (f32x4)0.f;

    const int srow = tid >> 3;                              // 0..31
    const int skc  = ((tid & 7) * 8) ^ ((srow & 7) << 3);   // swizzled source k-offset

    const int fr = lane & 15;
    const int kg = (lane >> 4) * 8;
    const int rsw = (fr & 7) << 3;

    for (int k0 = 0; k0 < K; k0 += 64) {
        #pragma unroll
        for (int it = 0; it < 4; ++it) {
            int row  = srow + it * 32;
            int arow = bm + row; if (arow >= M) arow = M - 1;
            const u16* ga = &A[(size_t)arow * K + k0 + skc];
            const u16* gb = &B[(size_t)(bn + row) * K + k0 + skc];
            __builtin_amdgcn_global_load_lds(
                (const __attribute__((address_space(1))) void*)ga,
                (__attribute__((address_space(3))) void*)((char*)As + it * 4096 + tid * 16),
                16, 0, 0);
            __builtin_amdgcn_global_load_lds(
                (const __attribute__((address_space(1))) void*)gb,
                (__attribute__((address_space(3))) void*)((char*)Bs + it * 4096 + tid * 16),
                16, 0, 0);
        }
        __syncthreads();

        #pragma unroll
        for (int ks = 0; ks < 2; ++ks) {
            const int col = (ks * 32 + kg) ^ rsw;
            f16x8 af[4], bfr[4];
            #pragma unroll
            for (int m2 = 0; m2 < 4; ++m2)
                af[m2] = *(const f16x8*)&As[(wr * 64 + m2 * 16 + fr) * 64 + col];
            #pragma unroll
            for (int n2 = 0; n2 < 4; ++n2)
                bfr[n2] = *(const f16x8*)&Bs[(wc * 64 + n2 * 16 + fr) * 64 + col];
            #pragma unroll
            for (int m2 = 0; m2 < 4; ++m2)
                #pragma unroll
                for (int n2 = 0; n2 < 4; ++n2)
                    acc[m2][n2] = __builtin_amdgcn_mfma_f32_16x16x32_f16(af[m2], bfr[n2], acc[m2][n2], 0, 0, 0);
        }
        __syncthreads();
    }

    const int fq = lane >> 4;
    float bv[4];
    if (BIAS) {
        #pragma unroll
        for (int n2 = 0; n2 < 4; ++n2) bv[n2] = bias[bn + wc * 64 + n2 * 16 + fr];
    }
    #pragma unroll
    for (int m2 = 0; m2 < 4; ++m2) {
        const int rb = bm + wr * 64 + m2 * 16;   // wave-uniform 16-row window
        #pragma unroll
        for (int n2 = 0; n2 < 4; ++n2) {
            int col = bn + wc * 64 + n2 * 16 + fr;
            float gv[4];
            #pragma unroll
            for (int j = 0; j < 4; ++j) {
                gv[j] = 0.f;
                int r = rb + fq * 4 + j;
                if (r < M) {
                    float v = acc[m2][n2][j];
                    if (BIAS) v += bv[n2];
                    if (OUTH) Ch[(size_t)r * N + col] = f2h(v);
                    else      Cf[(size_t)r * N + col] = v;
                    if (STATS) gv[j] = v;
                }
            }
            if (STATS) {
                bool uni = (rb + 15 < M) && (batch[rb] == batch[rb + 15]);
                if (uni) {
                    float s = gv[0] + gv[1] + gv[2] + gv[3];
                    float qq = gv[0]*gv[0] + gv[1]*gv[1] + gv[2]*gv[2] + gv[3]*gv[3];
                    s  += __shfl_xor(s, 16);  s  += __shfl_xor(s, 32);
                    qq += __shfl_xor(qq, 16); qq += __shfl_xor(qq, 32);
                    if (fq == 0) {
                        int gb2 = batch[rb];
                        atomicAdd(&sums [gb2 * CD + col], s);
                        atomicAdd(&sumsq[gb2 * CD + col], qq);
                    }
                } else {
                    int run = -1; float s = 0.f, qq = 0.f;
                    #pragma unroll
                    for (int j = 0; j < 4; ++j) {
                        int r = rb + fq * 4 + j;
                        if (r >= M) break;
                        int gb2 = batch[r];
                        if (gb2 != run) {
                            if (run >= 0) {
                                atomicAdd(&sums [run * CD + col], s);
                                atomicAdd(&sumsq[run * CD + col], qq);
                            }
                            run = gb2; s = 0.f; qq = 0.f;
                        }
                        s += gv[j]; qq += gv[j] * gv[j];
                    }
                    if (run >= 0) {
                        atomicAdd(&sums [run * CD + col], s);
                        atomicAdd(&sumsq[run * CD + col], qq);
                    }
                }
            }
        }
    }
}

template<bool BIAS, bool OUTH, bool STATS>
__global__ __launch_bounds__(256) void gemm_mfma(const u16* __restrict__ A,
                                                 const u16* __restrict__ B,
                                                 const float* __restrict__ bias,
                                                 float* __restrict__ Cf,
                                                 u16* __restrict__ Ch,
                                                 int M, int N, int K,
                                                 const int* __restrict__ batch,
                                                 float* __restrict__ sums,
                                                 float* __restrict__ sumsq) {
    __shared__ u16 As[128 * 64];
    __shared__ u16 Bs[128 * 64];
    gemm_tile<BIAS, OUTH, STATS>(A, B, bias, Cf, Ch, M, N, K,
                                 blockIdx.x * 128, blockIdx.y * 128, As, Bs,
                                 batch, sums, sumsq);
}

// All 6 Bc = wih_l @ ggc[l,i]^T  (768x256 each) in ONE launch: 72 blocks
__global__ __launch_bounds__(256) void gemm_bc_kernel(const u16* __restrict__ wih_h,
                                                      const u16* __restrict__ ggc_h,
                                                      u16* __restrict__ Bc) {
    __shared__ u16 As[128 * 64];
    __shared__ u16 Bs[128 * 64];
    int b = blockIdx.x;            // 0..71
    int mat = b / 12, rem = b % 12;
    int bx = rem % 6, by = rem / 6;
    gemm_tile<false, true, false>(wih_h + (size_t)(mat >> 1) * 3 * CD * CD,
                                  ggc_h + (size_t)mat * CD * CD,
                                  nullptr, nullptr,
                                  Bc + (size_t)mat * 3 * CD * CD,
                                  3 * CD, CD, CD, bx * 128, by * 128, As, Bs,
                                  nullptr, nullptr, nullptr);
}

// ---------------------------------------------------------------------------
// FUSED gate-GEMM + GRU (v4 structure) + optional STATS epilogue.
// ho (GRU blend input g0[row][col]) is captured from the Ag0 LDS quarter when
// k0 == jb (that staged quarter holds exactly the epilogue's columns) ->
// removes ~5.1M scattered 2B global loads per dispatch.
// STATS: gelu(res) in f32 -> mout + per-(graph,col) partial sums; raw state
// g1 dead on STATS iterations -> no store.
// ---------------------------------------------------------------------------
template<bool STATS>
__global__ __launch_bounds__(256) void fused_gate_gru_kernel(
        const u16* __restrict__ ag,    // agg(g0) [NN][256]
        const u16* __restrict__ g0,    // current state [NN][256]
        const u16* __restrict__ Bc,    // combined wih@W^T [768][256]
        const u16* __restrict__ whh,   // [768][256]
        const float* __restrict__ bih, // [768]
        const float* __restrict__ bhh, // [768]
        u16* __restrict__ g1,          // new state out (!STATS)
        const int* __restrict__ batch, // [NN] (STATS)
        u16* __restrict__ mout,        // gelu out (STATS)
        float* __restrict__ sums,      // [GG][CD] (STATS)
        float* __restrict__ sumsq) {   // [GG][CD] (STATS)
    __shared__ u16 S[32768];           // 64 KB
    u16* Aag = S;                      // 64x64
    u16* Ag0 = S + 4096;               // 64x64
    u16* SBc = S + 8192;               // 192x64
    u16* SWh = S + 20480;              // 192x64

    const int nwg = gridDim.x;         // 1252
    const int q = nwg >> 3, r = nwg & 7;
    int xcd = blockIdx.x & 7, idx = blockIdx.x >> 3;
    int nid = (xcd < r ? xcd * (q + 1) : r * (q + 1) + (xcd - r) * q) + idx;
    const int bm = (nid >> 2) * 64;    // row base
    const int jb = (nid & 3) * 64;     // gru-col base

    const int tid  = threadIdx.x;
    const int lane = tid & 63;
    const int wave = tid >> 6;         // 0..3
    const int wrow = wave >> 1;
    const int wcol = wave & 1;
    const int fr = lane & 15;
    const int fq = lane >> 4;
    const int kg = fq * 8;
    const int rsw = (fr & 7) << 3;

    const int srow = tid >> 3;                              // 0..31
    const int skc  = ((tid & 7) * 8) ^ ((srow & 7) << 3);   // swizzled src k-off

    f32x4 acc[6][2][2];
    #pragma unroll
    for (int g = 0; g < 6; ++g)
        #pragma unroll
        for (int m = 0; m < 2; ++m)
            #pragma unroll
            for (int n = 0; n < 2; ++n) acc[g][m][n] = (f32x4)0.f;

    u16 hov[2][2][4];                  // captured g0[row][col] for GRU blend

    for (int k0 = 0; k0 < CD; k0 += 64) {
        #pragma unroll
        for (int it = 0; it < 2; ++it) {
            int arow = bm + it * 32 + srow; if (arow >= NN) arow = NN - 1;
            __builtin_amdgcn_global_load_lds(
                (const __attribute__((address_space(1))) void*)&ag[(size_t)arow * CD + k0 + skc],
                (__attribute__((address_space(3))) void*)((char*)Aag + it * 4096 + tid * 16),
                16, 0, 0);
            __builtin_amdgcn_global_load_lds(
                (const __attribute__((address_space(1))) void*)&g0[(size_t)arow * CD + k0 + skc],
                (__attribute__((address_space(3))) void*)((char*)Ag0 + it * 4096 + tid * 16),
                16, 0, 0);
        }
        #pragma unroll
        for (int p = 0; p < 3; ++p) {
            #pragma unroll
            for (int hf = 0; hf < 2; ++hf) {
                int grow = p * 256 + jb + hf * 32 + srow;
                __builtin_amdgcn_global_load_lds(
                    (const __attribute__((address_space(1))) void*)&Bc[(size_t)grow * CD + k0 + skc],
                    (__attribute__((address_space(3))) void*)((char*)SBc + p * 8192 + hf * 4096 + tid * 16),
                    16, 0, 0);
                __builtin_amdgcn_global_load_lds(
                    (const __attribute__((address_space(1))) void*)&whh[(size_t)grow * CD + k0 + skc],
                    (__attribute__((address_space(3))) void*)((char*)SWh + p * 8192 + hf * 4096 + tid * 16),
                    16, 0, 0);
            }
        }
        __syncthreads();

        #pragma unroll
        for (int ks = 0; ks < 2; ++ks) {
            const int col = (ks * 32 + kg) ^ rsw;
            f16x8 aa[2], gg[2];
            #pragma unroll
            for (int m = 0; m < 2; ++m) {
                int arl = (wrow * 32 + m * 16 + fr) * 64 + col;
                aa[m] = *(const f16x8*)&Aag[arl];
                gg[m] = *(const f16x8*)&Ag0[arl];
            }
            #pragma unroll
            for (int p = 0; p < 3; ++p) {
                #pragma unroll
                for (int n = 0; n < 2; ++n) {
                    int brl = p * 4096 + (wcol * 32 + n * 16 + fr) * 64 + col;
                    f16x8 bc = *(const f16x8*)&SBc[brl];
                    f16x8 bw = *(const f16x8*)&SWh[brl];
                    #pragma unroll
                    for (int m = 0; m < 2; ++m) {
                        acc[p][m][n]     = __builtin_amdgcn_mfma_f32_16x16x32_f16(aa[m], bc, acc[p][m][n], 0, 0, 0);
                        acc[3 + p][m][n] = __builtin_amdgcn_mfma_f32_16x16x32_f16(gg[m], bw, acc[3 + p][m][n], 0, 0, 0);
                    }
                }
            }
        }
        // capture ho from the quarter that holds the epilogue's columns
        if (k0 == jb) {
            #pragma unroll
            for (int m = 0; m < 2; ++m)
                #pragma unroll
                for (int jj = 0; jj < 4; ++jj) {
                    const int rloc = wrow * 32 + m * 16 + fq * 4 + jj;
                    const int sw = (rloc & 7) << 3;
                    #pragma unroll
                    for (int n = 0; n < 2; ++n)
                        hov[m][n][jj] = Ag0[rloc * 64 + ((wcol * 32 + n * 16 + fr) ^ sw)];
                }
        }
        __syncthreads();
    }

    float bI[3][2], bH[3][2];
    #pragma unroll
    for (int p = 0; p < 3; ++p)
        #pragma unroll
        for (int n = 0; n < 2; ++n) {
            int gc = p * 256 + jb + wcol * 32 + n * 16 + fr;
            bI[p][n] = bih[gc];
            bH[p][n] = bhh[gc];
        }

    #pragma unroll
    for (int m = 0; m < 2; ++m) {
        const int rb = bm + wrow * 32 + m * 16;   // wave-uniform window
        #pragma unroll
        for (int n = 0; n < 2; ++n) {
            int col = jb + wcol * 32 + n * 16 + fr;
            float gv[4];
            #pragma unroll
            for (int jj = 0; jj < 4; ++jj) {
                gv[jj] = 0.f;
                int row = rb + fq * 4 + jj;
                if (row >= NN) continue;
                float Ir = acc[0][m][n][jj] + bI[0][n];
                float Iz = acc[1][m][n][jj] + bI[1][n];
                float In = acc[2][m][n][jj] + bI[2][n];
                float Hr = acc[3][m][n][jj] + bH[0][n];
                float Hz = acc[4][m][n][jj] + bH[1][n];
                float Hn = acc[5][m][n][jj] + bH[2][n];
                float rr = 1.f / (1.f + expf(-(Ir + Hr)));
                float zz = 1.f / (1.f + expf(-(Iz + Hz)));
                float nv = tanhf(In + rr * Hn);
                float ho = h2f(hov[m][n][jj]);
                float res = (1.f - zz) * nv + zz * ho;
                if (!STATS) {
                    g1[(size_t)row * CD + col] = f2h(res);
                } else {
                    float val = 0.5f * res * (1.f + erff(res * 0.70710678118654752f));
                    mout[(size_t)row * CD + col] = f2h(val);
                    gv[jj] = val;
                }
            }
            if (STATS) {
                bool uni = (rb + 15 < NN) && (batch[rb] == batch[rb + 15]);
                if (uni) {
                    float s = gv[0] + gv[1] + gv[2] + gv[3];
                    float qq = gv[0]*gv[0] + gv[1]*gv[1] + gv[2]*gv[2] + gv[3]*gv[3];
                    s  += __shfl_xor(s, 16);  s  += __shfl_xor(s, 32);
                    qq += __shfl_xor(qq, 16); qq += __shfl_xor(qq, 32);
                    if (fq == 0) {
                        int gb2 = batch[rb];
                        atomicAdd(&sums [gb2 * CD + col], s);
                        atomicAdd(&sumsq[gb2 * CD + col], qq);
                    }
                } else {
                    int run = -1; float s = 0.f, qq = 0.f;
                    #pragma unroll
                    for (int jj = 0; jj < 4; ++jj) {
                        int row = rb + fq * 4 + jj;
                        if (row >= NN) break;
                        int gb2 = batch[row];
                        if (gb2 != run) {
                            if (run >= 0) {
                                atomicAdd(&sums [run * CD + col], s);
                                atomicAdd(&sumsq[run * CD + col], qq);
                            }
                            run = gb2; s = 0.f; qq = 0.f;
                        }
                        s += gv[jj]; qq += gv[jj] * gv[jj];
                    }
                    if (run >= 0) {
                        atomicAdd(&sums [run * CD + col], s);
                        atomicAdd(&sumsq[run * CD + col], qq);
                    }
                }
            }
        }
    }
}

// ---------------------------------------------------------------------------
// Edge aggregation: WAVE-per-node, register-only, 16B/lane (u16x8).
// CHN=256: 32 lanes/node, 2 nodes/wave.  CHN=128: 16 lanes/node, 4 nodes/wave.
// ---------------------------------------------------------------------------
template<int CHN, bool GCN>
__global__ __launch_bounds__(256) void agg_kernel(const u16* __restrict__ feat,
                                                  const int* __restrict__ offsets,
                                                  const int* __restrict__ srcs,
                                                  const float* __restrict__ wts,
                                                  const float* __restrict__ dinv,
                                                  u16* __restrict__ outp) {
    constexpr int LPN = CHN / 8;       // lanes per node
    constexpr int NPW = 64 / LPN;      // nodes per wave
    constexpr int NPB = 4 * NPW;       // nodes per block
    const int lane = threadIdx.x & 63;
    const int wave = threadIdx.x >> 6;
    const int sub  = lane / LPN;
    const int ln   = lane % LPN;
    const int v = blockIdx.x * NPB + wave * NPW + sub;
    if (v >= NN) return;

    const int o0 = offsets[v], o1 = offsets[v + 1];
    float a[8];
    #pragma unroll
    for (int t = 0; t < 8; ++t) a[t] = 0.f;
    int o = o0;
    for (; o + 4 <= o1; o += 4) {
        int s0 = srcs[o], s1 = srcs[o + 1], s2 = srcs[o + 2], s3 = srcs[o + 3];
        u16x8 m0 = *(const u16x8*)&feat[(size_t)s0 * CHN + ln * 8];
        u16x8 m1 = *(const u16x8*)&feat[(size_t)s1 * CHN + ln * 8];
        u16x8 m2 = *(const u16x8*)&feat[(size_t)s2 * CHN + ln * 8];
        u16x8 m3 = *(const u16x8*)&feat[(size_t)s3 * CHN + ln * 8];
        float w0 = GCN ? wts[o]     : 1.f;
        float w1 = GCN ? wts[o + 1] : 1.f;
        float w2 = GCN ? wts[o + 2] : 1.f;
        float w3 = GCN ? wts[o + 3] : 1.f;
        #pragma unroll
        for (int t = 0; t < 8; ++t)
            a[t] += w0 * h2f(m0[t]) + w1 * h2f(m1[t]) + w2 * h2f(m2[t]) + w3 * h2f(m3[t]);
    }
    for (; o < o1; ++o) {
        int s = srcs[o];
        float w = GCN ? wts[o] : 1.f;
        u16x8 mv = *(const u16x8*)&feat[(size_t)s * CHN + ln * 8];
        #pragma unroll
        for (int t = 0; t < 8; ++t) a[t] += w * h2f(mv[t]);
    }
    if (GCN) {
        float dv = dinv[v];
        u16x8 sv = *(const u16x8*)&feat[(size_t)v * CHN + ln * 8];
        #pragma unroll
        for (int t = 0; t < 8; ++t) a[t] = dv * a[t] + dv * dv * h2f(sv[t]);
    }
    u16x8 ov;
    #pragma unroll
    for (int t = 0; t < 8; ++t) ov[t] = f2h(a[t]);
    *(u16x8*)&outp[(size_t)v * CHN + ln * 8] = ov;
}

// ---------------------------------------------------------------------------
// GN apply with inline finalize; writes h_h only (post-norm state == residual).
// ---------------------------------------------------------------------------
template<bool RES>
__global__ void gn_apply_kernel(const u16* __restrict__ x,
                                const int* __restrict__ batch,
                                const float* __restrict__ sums,
                                const float* __restrict__ sumsq,
                                const int* __restrict__ cntg,
                                const float* __restrict__ w,
                                const float* __restrict__ ms,
                                const float* __restrict__ bvec,
                                u16* __restrict__ h_h) {
    int i = blockIdx.x * blockDim.x + threadIdx.x;   // over NN*64
    if (i >= NN * (CD / 4)) return;
    int v = i >> 6, c4 = (i & 63) << 2;
    int gb = batch[v];
    size_t idx = (size_t)v * CD + c4;
    ushort4 xv = *(const ushort4*)&x[idx];
    float4 sm = *(const float4*)&sums[gb * CD + c4];
    float4 sq = *(const float4*)&sumsq[gb * CD + c4];
    float4 wv = *(const float4*)&w[c4];
    float4 mv = *(const float4*)&ms[c4];
    float4 bb = *(const float4*)&bvec[c4];
    float rc = 1.0f / fmaxf((float)cntg[gb], 1.0f);
    float4 val;
    #pragma unroll
    for (int t = 0; t < 4; ++t) {
        float mean = (&sm.x)[t] * rc;
        float ex2  = (&sq.x)[t] * rc;
        float msm  = (&mv.x)[t] * mean;
        float var  = ex2 - 2.f * msm * mean + msm * msm;
        float scale = (&wv.x)[t] * rsqrtf(var + EPSV);
        (&val.x)[t] = (h2f((&xv.x)[t]) - msm) * scale + (&bb.x)[t];
    }
    if (RES) {
        ushort4 hv = *(const ushort4*)&h_h[idx];
        val.x += h2f(hv.x); val.y += h2f(hv.y); val.z += h2f(hv.z); val.w += h2f(hv.w);
    }
    ushort4 ov; ov.x = f2h(val.x); ov.y = f2h(val.y); ov.z = f2h(val.z); ov.w = f2h(val.w);
    *(ushort4*)&h_h[idx] = ov;
}

// ---------------------------------------------------------------------------
// Host
// ---------------------------------------------------------------------------
extern "C" void kernel_launch(void* const* d_in, const int* in_sizes, int n_in,
                              void* d_out, int out_size, void* d_ws, size_t ws_size,
                              hipStream_t stream) {
    const float* x      = (const float*)d_in[0];
    const int*   ei     = (const int*)d_in[1];
    const int*   batch  = (const int*)d_in[2];
    const float* gcn_w  = (const float*)d_in[3];
    const float* gcn_b  = (const float*)d_in[4];
    const float* gn0_w  = (const float*)d_in[5];
    const float* gn0_b  = (const float*)d_in[6];
    const float* gn0_ms = (const float*)d_in[7];
    const float* ggc_w  = (const float*)d_in[8];
    const float* gru_wih = (const float*)d_in[9];
    const float* gru_whh = (const float*)d_in[10];
    const float* gru_bih = (const float*)d_in[11];
    const float* gru_bhh = (const float*)d_in[12];
    const float* gn_w   = (const float*)d_in[13];
    const float* gn_b   = (const float*)d_in[14];
    const float* gn_ms  = (const float*)d_in[15];
    const float* lin_w  = (const float*)d_in[16];
    const float* lin_b  = (const float*)d_in[17];
    float* outp = (float*)d_out;

    const int* srcv = ei;
    const int* dstv = ei + EE;

    char* base = (char*)d_ws;
    size_t off = 0;
    auto alloc = [&](size_t bytes) -> void* {
        void* p = base + off;
        off = (off + bytes + 255) & ~(size_t)255;
        return p;
    };

    // ---- zeroed-at-start region ----
    int*   counts   = (int*)alloc(NN * 4);
    int*   cursor   = (int*)alloc(NN * 4);
    int*   cntg     = (int*)alloc(GG * 4);
    float* sums_all = (float*)alloc((size_t)4 * 2 * GG * CD * 4);  // 4 stages x (sums,sumsq)
    size_t zero_end = off;

    int*   offsets = (int*)alloc((NN + 1) * 4);
    int*   srcs    = (int*)alloc((size_t)EE * 4);
    float* wts     = (float*)alloc((size_t)EE * 4);
    float* dinv    = (float*)alloc(NN * 4);
    // f16 weights
    u16* gcn_wt = (u16*)alloc((size_t)CD * IND * 2);
    u16* ggc_h  = (u16*)alloc((size_t)6 * CD * CD * 2);
    u16* wih_h  = (u16*)alloc((size_t)LL * 3 * CD * CD * 2);
    u16* whh_h  = (u16*)alloc((size_t)LL * 3 * CD * CD * 2);
    u16* lin_wt = (u16*)alloc((size_t)OUTD * CD * 2);
    u16* Bc     = (u16*)alloc((size_t)6 * 3 * CD * CD * 2);
    // activations (all f16)
    u16* x_h  = (u16*)alloc((size_t)NN * IND * 2);
    u16* ax_h = (u16*)alloc((size_t)NN * IND * 2);
    u16* gmid = (u16*)alloc((size_t)NN * CD * 2);
    u16* h_h  = (u16*)alloc((size_t)NN * CD * 2);
    u16* m_h  = (u16*)alloc((size_t)NN * CD * 2);
    u16* a_h  = (u16*)alloc((size_t)NN * CD * 2);

    // ---- CSR build + per-graph counts ----
    hipMemsetAsync(counts, 0, zero_end, stream);
    hist_kernel<<<512, 256, 0, stream>>>(dstv, batch, counts, cntg);
    scan_kernel<<<1, 1024, 0, stream>>>(counts, offsets, dinv);
    fill_kernel<<<(EE + 255) / 256, 256, 0, stream>>>(srcv, dstv, offsets, cursor, dinv, srcs, wts);

    // ---- fused conversions (x + all weights) ----
    {
        const int tot4 = NN * IND / 4 + CD * IND / 4 + 6 * CD * CD / 4
                       + 2 * (LL * 3 * CD * CD / 4) + OUTD * CD / 4;
        conv_all_kernel<<<(tot4 + 255) / 256, 256, 0, stream>>>(
            x, gcn_w, ggc_w, gru_wih, gru_whh, lin_w,
            x_h, gcn_wt, ggc_h, wih_h, whh_h, lin_wt);
    }

    // ---- all 6 Bc = wih @ ggc^T in one launch ----
    gemm_bc_kernel<<<72, 256, 0, stream>>>(wih_h, ggc_h, Bc);

    const int gmx = (NN + 127) / 128;      // 157
    const int nv4 = (NN * (CD / 4) + 255) / 256;
    const int nfused = ((NN + 63) / 64) * 4;  // 1252
    const int nagg256 = (NN + 7) / 8;      // 8 nodes/block (2/wave)
    const int nagg128 = (NN + 15) / 16;    // 16 nodes/block (4/wave)

    // ---- GCNConv: aggregate x (128ch), then GEMM with fused stage-0 stats ----
    float* sums0  = sums_all;
    float* sumsq0 = sums0 + GG * CD;
    agg_kernel<IND, true><<<nagg128, 256, 0, stream>>>(x_h, offsets, srcs, wts, dinv, ax_h);
    gemm_mfma<true, true, true><<<dim3(gmx, CD / 128), 256, 0, stream>>>(
        ax_h, gcn_wt, gcn_b, nullptr, a_h, NN, CD, IND, batch, sums0, sumsq0);
    gn_apply_kernel<false><<<nv4, 256, 0, stream>>>(a_h, batch, sums0, sumsq0, cntg,
                                                    gn0_w, gn0_ms, gn0_b, h_h);

    // ---- gated blocks (state lives in h_h after each norm) ----
    for (int l = 0; l < LL; ++l) {
        const u16* whh = whh_h + (size_t)l * 3 * CD * CD;
        const float* bih = gru_bih + (size_t)l * 3 * CD;
        const float* bhh = gru_bhh + (size_t)l * 3 * CD;
        float* sums  = sums_all + (size_t)(1 + l) * 2 * GG * CD;
        float* sumsq = sums + GG * CD;
        const u16* Bc0 = Bc + ((size_t)l * 2 + 0) * 3 * CD * CD;
        const u16* Bc1 = Bc + ((size_t)l * 2 + 1) * 3 * CD * CD;

        // i = 0: state h_h -> gmid
        agg_kernel<CD, false><<<nagg256, 256, 0, stream>>>(h_h, offsets, srcs, wts, dinv, a_h);
        fused_gate_gru_kernel<false><<<nfused, 256, 0, stream>>>(
            a_h, h_h, Bc0, whh, bih, bhh, gmid, nullptr, nullptr, nullptr, nullptr);
        // i = 1: state gmid -> (gelu m_h + stats); raw state dead
        agg_kernel<CD, false><<<nagg256, 256, 0, stream>>>(gmid, offsets, srcs, wts, dinv, a_h);
        fused_gate_gru_kernel<true><<<nfused, 256, 0, stream>>>(
            a_h, gmid, Bc1, whh, bih, bhh, nullptr, batch, m_h, sums, sumsq);

        gn_apply_kernel<true><<<nv4, 256, 0, stream>>>(m_h, batch, sums, sumsq, cntg,
                                                       gn_w + l * CD, gn_ms + l * CD, gn_b + l * CD, h_h);
    }

    // ---- final linear on f16 h ----
    gemm_mfma<true, false, false><<<dim3(gmx, OUTD / 128), 256, 0, stream>>>(
        h_h, lin_wt, lin_b, outp, nullptr, NN, OUTD, CD, nullptr, nullptr, nullptr);
}

// Round 18
// 586.639 us; speedup vs baseline: 1.2422x; 1.2422x over previous
//
#include <hip/hip_runtime.h>
#include <math.h>

typedef unsigned short u16;
typedef _Float16 f16;
typedef __attribute__((ext_vector_type(8))) _Float16 f16x8;
typedef __attribute__((ext_vector_type(4))) float f32x4;
typedef __attribute__((ext_vector_type(8))) unsigned short u16x8;

constexpr int NN   = 20000;
constexpr int EE   = 320000;
constexpr int CD   = 256;
constexpr int IND  = 128;
constexpr int OUTD = 128;
constexpr int LL   = 3;
constexpr int GG   = 16;
constexpr float EPSV = 1e-5f;

__device__ __forceinline__ u16 f2h(float f) {
    union { f16 h; u16 u; } v; v.h = (f16)f; return v.u;
}
__device__ __forceinline__ float h2f(u16 u) {
    union { u16 u; f16 h; } v; v.u = u; return (float)v.h;
}

// ---------------------------------------------------------------------------
// CSR build: fused edge histogram + batch histogram
// ---------------------------------------------------------------------------
__global__ void hist_kernel(const int* __restrict__ dst, const int* __restrict__ batch,
                            int* __restrict__ counts, int* __restrict__ cntg) {
    __shared__ int loc[GG];
    if (threadIdx.x < GG) loc[threadIdx.x] = 0;
    __syncthreads();
    int stride = gridDim.x * blockDim.x;
    for (int e = blockIdx.x * blockDim.x + threadIdx.x; e < EE; e += stride)
        atomicAdd(&counts[dst[e]], 1);
    for (int i = blockIdx.x * blockDim.x + threadIdx.x; i < NN; i += stride)
        atomicAdd(&loc[batch[i]], 1);
    __syncthreads();
    if (threadIdx.x < GG) atomicAdd(&cntg[threadIdx.x], loc[threadIdx.x]);
}

__global__ __launch_bounds__(1024) void scan_kernel(const int* __restrict__ counts,
                                                    int* __restrict__ offsets,
                                                    float* __restrict__ dinv) {
    __shared__ int ls[1024];
    int t = threadIdx.x;
    const int CHK = (NN + 1023) / 1024;
    int begin = t * CHK;
    int end   = begin + CHK; if (end > NN) end = NN;
    int s = 0;
    for (int i = begin; i < end && i < NN; ++i) s += counts[i];
    ls[t] = s;
    __syncthreads();
    for (int off = 1; off < 1024; off <<= 1) {
        int v = (t >= off) ? ls[t - off] : 0;
        __syncthreads();
        ls[t] += v;
        __syncthreads();
    }
    int run = ls[t] - s;
    for (int i = begin; i < end && i < NN; ++i) {
        offsets[i] = run;
        int c = counts[i];
        run += c;
        dinv[i] = rsqrtf((float)(c + 1));
    }
    if (t == 1023) offsets[NN] = run;
}

__global__ void fill_kernel(const int* __restrict__ src, const int* __restrict__ dst,
                            const int* __restrict__ offsets, int* __restrict__ cursor,
                            const float* __restrict__ dinv,
                            int* __restrict__ srcs, float* __restrict__ wts) {
    int e = blockIdx.x * blockDim.x + threadIdx.x;
    if (e >= EE) return;
    int d = dst[e];
    int p = atomicAdd(&cursor[d], 1);
    int pos = offsets[d] + p;
    int s = src[e];
    srcs[pos] = s;
    wts[pos]  = dinv[s];
}

// ---------------------------------------------------------------------------
// Fused f32 -> f16 conversion of x + all weights (one launch)
// ---------------------------------------------------------------------------
__global__ void conv_all_kernel(const float* __restrict__ x,   const float* __restrict__ gcn_w,
                                const float* __restrict__ ggc, const float* __restrict__ wih,
                                const float* __restrict__ whh, const float* __restrict__ lin,
                                u16* __restrict__ x_h,  u16* __restrict__ gcn_h,
                                u16* __restrict__ ggc_h, u16* __restrict__ wih_h,
                                u16* __restrict__ whh_h, u16* __restrict__ lin_h) {
    const int b0 = NN * IND / 4;
    const int b1 = b0 + CD * IND / 4;
    const int b2 = b1 + 6 * CD * CD / 4;
    const int b3 = b2 + LL * 3 * CD * CD / 4;
    const int b4 = b3 + LL * 3 * CD * CD / 4;
    const int b5 = b4 + OUTD * CD / 4;
    int i = blockIdx.x * blockDim.x + threadIdx.x;
    if (i >= b5) return;
    const float* src; u16* dst; int base;
    if (i < b0)      { src = x;     dst = x_h;   base = 0;  }
    else if (i < b1) { src = gcn_w; dst = gcn_h; base = b0; }
    else if (i < b2) { src = ggc;   dst = ggc_h; base = b1; }
    else if (i < b3) { src = wih;   dst = wih_h; base = b2; }
    else if (i < b4) { src = whh;   dst = whh_h; base = b3; }
    else             { src = lin;   dst = lin_h; base = b4; }
    int j = i - base;
    float4 v = ((const float4*)src)[j];
    ushort4 o;
    o.x = f2h(v.x); o.y = f2h(v.y); o.z = f2h(v.z); o.w = f2h(v.w);
    ((ushort4*)dst)[j] = o;
}

// ---------------------------------------------------------------------------
// f16 MFMA GEMM tile body: C[M,N] = A[M,K] * B^T (B stored [N,K]) (+bias)
// 128x128 tile, BK=64, 4 waves, global_load_lds w16, XOR-swizzled LDS (T2).
// STATS: also accumulate per-(graph,col) sums/sumsq of the f32 outputs.
// ---------------------------------------------------------------------------
template<bool BIAS, bool OUTH, bool STATS>
__device__ __forceinline__ void gemm_tile(const u16* __restrict__ A,
                                          const u16* __restrict__ B,
                                          const float* __restrict__ bias,
                                          float* __restrict__ Cf,
                                          u16* __restrict__ Ch,
                                          int M, int N, int K,
                                          int bm, int bn,
                                          u16* As, u16* Bs,
                                          const int* __restrict__ batch,
                                          float* __restrict__ sums,
                                          float* __restrict__ sumsq) {
    const int tid  = threadIdx.x;
    const int lane = tid & 63;
    const int wave = tid >> 6;
    const int wr = wave >> 1, wc = wave & 1;

    f32x4 acc[4][4];
    #pragma unroll
    for (int i = 0; i < 4; ++i)
        #pragma unroll
        for (int j = 0; j < 4; ++j) acc[i][j] = (f32x4)0.f;

    const int srow = tid >> 3;                              // 0..31
    const int skc  = ((tid & 7) * 8) ^ ((srow & 7) << 3);   // swizzled source k-offset

    const int fr = lane & 15;
    const int kg = (lane >> 4) * 8;
    const int rsw = (fr & 7) << 3;

    for (int k0 = 0; k0 < K; k0 += 64) {
        #pragma unroll
        for (int it = 0; it < 4; ++it) {
            int row  = srow + it * 32;
            int arow = bm + row; if (arow >= M) arow = M - 1;
            const u16* ga = &A[(size_t)arow * K + k0 + skc];
            const u16* gb = &B[(size_t)(bn + row) * K + k0 + skc];
            __builtin_amdgcn_global_load_lds(
                (const __attribute__((address_space(1))) void*)ga,
                (__attribute__((address_space(3))) void*)((char*)As + it * 4096 + tid * 16),
                16, 0, 0);
            __builtin_amdgcn_global_load_lds(
                (const __attribute__((address_space(1))) void*)gb,
                (__attribute__((address_space(3))) void*)((char*)Bs + it * 4096 + tid * 16),
                16, 0, 0);
        }
        __syncthreads();

        #pragma unroll
        for (int ks = 0; ks < 2; ++ks) {
            const int col = (ks * 32 + kg) ^ rsw;
            f16x8 af[4], bfr[4];
            #pragma unroll
            for (int m2 = 0; m2 < 4; ++m2)
                af[m2] = *(const f16x8*)&As[(wr * 64 + m2 * 16 + fr) * 64 + col];
            #pragma unroll
            for (int n2 = 0; n2 < 4; ++n2)
                bfr[n2] = *(const f16x8*)&Bs[(wc * 64 + n2 * 16 + fr) * 64 + col];
            #pragma unroll
            for (int m2 = 0; m2 < 4; ++m2)
                #pragma unroll
                for (int n2 = 0; n2 < 4; ++n2)
                    acc[m2][n2] = __builtin_amdgcn_mfma_f32_16x16x32_f16(af[m2], bfr[n2], acc[m2][n2], 0, 0, 0);
        }
        __syncthreads();
    }

    const int fq = lane >> 4;
    float bv[4];
    if (BIAS) {
        #pragma unroll
        for (int n2 = 0; n2 < 4; ++n2) bv[n2] = bias[bn + wc * 64 + n2 * 16 + fr];
    }
    #pragma unroll
    for (int m2 = 0; m2 < 4; ++m2) {
        const int rb = bm + wr * 64 + m2 * 16;   // wave-uniform 16-row window
        #pragma unroll
        for (int n2 = 0; n2 < 4; ++n2) {
            int col = bn + wc * 64 + n2 * 16 + fr;
            float gv[4];
            #pragma unroll
            for (int j = 0; j < 4; ++j) {
                gv[j] = 0.f;
                int r = rb + fq * 4 + j;
                if (r < M) {
                    float v = acc[m2][n2][j];
                    if (BIAS) v += bv[n2];
                    if (OUTH) Ch[(size_t)r * N + col] = f2h(v);
                    else      Cf[(size_t)r * N + col] = v;
                    if (STATS) gv[j] = v;
                }
            }
            if (STATS) {
                bool uni = (rb + 15 < M) && (batch[rb] == batch[rb + 15]);
                if (uni) {
                    float s = gv[0] + gv[1] + gv[2] + gv[3];
                    float qq = gv[0]*gv[0] + gv[1]*gv[1] + gv[2]*gv[2] + gv[3]*gv[3];
                    s  += __shfl_xor(s, 16);  s  += __shfl_xor(s, 32);
                    qq += __shfl_xor(qq, 16); qq += __shfl_xor(qq, 32);
                    if (fq == 0) {
                        int gb2 = batch[rb];
                        atomicAdd(&sums [gb2 * CD + col], s);
                        atomicAdd(&sumsq[gb2 * CD + col], qq);
                    }
                } else {
                    int run = -1; float s = 0.f, qq = 0.f;
                    #pragma unroll
                    for (int j = 0; j < 4; ++j) {
                        int r = rb + fq * 4 + j;
                        if (r >= M) break;
                        int gb2 = batch[r];
                        if (gb2 != run) {
                            if (run >= 0) {
                                atomicAdd(&sums [run * CD + col], s);
                                atomicAdd(&sumsq[run * CD + col], qq);
                            }
                            run = gb2; s = 0.f; qq = 0.f;
                        }
                        s += gv[j]; qq += gv[j] * gv[j];
                    }
                    if (run >= 0) {
                        atomicAdd(&sums [run * CD + col], s);
                        atomicAdd(&sumsq[run * CD + col], qq);
                    }
                }
            }
        }
    }
}

template<bool BIAS, bool OUTH, bool STATS>
__global__ __launch_bounds__(256) void gemm_mfma(const u16* __restrict__ A,
                                                 const u16* __restrict__ B,
                                                 const float* __restrict__ bias,
                                                 float* __restrict__ Cf,
                                                 u16* __restrict__ Ch,
                                                 int M, int N, int K,
                                                 const int* __restrict__ batch,
                                                 float* __restrict__ sums,
                                                 float* __restrict__ sumsq) {
    __shared__ u16 As[128 * 64];
    __shared__ u16 Bs[128 * 64];
    gemm_tile<BIAS, OUTH, STATS>(A, B, bias, Cf, Ch, M, N, K,
                                 blockIdx.x * 128, blockIdx.y * 128, As, Bs,
                                 batch, sums, sumsq);
}

// All 6 Bc = wih_l @ ggc[l,i]^T  (768x256 each) in ONE launch: 72 blocks
__global__ __launch_bounds__(256) void gemm_bc_kernel(const u16* __restrict__ wih_h,
                                                      const u16* __restrict__ ggc_h,
                                                      u16* __restrict__ Bc) {
    __shared__ u16 As[128 * 64];
    __shared__ u16 Bs[128 * 64];
    int b = blockIdx.x;            // 0..71
    int mat = b / 12, rem = b % 12;
    int bx = rem % 6, by = rem / 6;
    gemm_tile<false, true, false>(wih_h + (size_t)(mat >> 1) * 3 * CD * CD,
                                  ggc_h + (size_t)mat * CD * CD,
                                  nullptr, nullptr,
                                  Bc + (size_t)mat * 3 * CD * CD,
                                  3 * CD, CD, CD, bx * 128, by * 128, As, Bs,
                                  nullptr, nullptr, nullptr);
}

// ---------------------------------------------------------------------------
// FUSED gate-GEMM + GRU (v4 structure, round-16 proven: 45.4us plain /
// 59.6us STATS, 112 VGPR).  STATS: gelu(res) in f32 -> mout + per-(graph,col)
// partial sums; raw state g1 dead on STATS iterations -> no store.
// ---------------------------------------------------------------------------
template<bool STATS>
__global__ __launch_bounds__(256) void fused_gate_gru_kernel(
        const u16* __restrict__ ag,    // agg(g0) [NN][256]
        const u16* __restrict__ g0,    // current state [NN][256]
        const u16* __restrict__ Bc,    // combined wih@W^T [768][256]
        const u16* __restrict__ whh,   // [768][256]
        const float* __restrict__ bih, // [768]
        const float* __restrict__ bhh, // [768]
        u16* __restrict__ g1,          // new state out (!STATS)
        const int* __restrict__ batch, // [NN] (STATS)
        u16* __restrict__ mout,        // gelu out (STATS)
        float* __restrict__ sums,      // [GG][CD] (STATS)
        float* __restrict__ sumsq) {   // [GG][CD] (STATS)
    __shared__ u16 S[32768];           // 64 KB
    u16* Aag = S;                      // 64x64
    u16* Ag0 = S + 4096;               // 64x64
    u16* SBc = S + 8192;               // 192x64
    u16* SWh = S + 20480;              // 192x64

    const int nwg = gridDim.x;         // 1252
    const int q = nwg >> 3, r = nwg & 7;
    int xcd = blockIdx.x & 7, idx = blockIdx.x >> 3;
    int nid = (xcd < r ? xcd * (q + 1) : r * (q + 1) + (xcd - r) * q) + idx;
    const int bm = (nid >> 2) * 64;    // row base
    const int jb = (nid & 3) * 64;     // gru-col base

    const int tid  = threadIdx.x;
    const int lane = tid & 63;
    const int wave = tid >> 6;         // 0..3
    const int wrow = wave >> 1;
    const int wcol = wave & 1;
    const int fr = lane & 15;
    const int fq = lane >> 4;
    const int kg = fq * 8;
    const int rsw = (fr & 7) << 3;

    const int srow = tid >> 3;                              // 0..31
    const int skc  = ((tid & 7) * 8) ^ ((srow & 7) << 3);   // swizzled src k-off

    f32x4 acc[6][2][2];
    #pragma unroll
    for (int g = 0; g < 6; ++g)
        #pragma unroll
        for (int m = 0; m < 2; ++m)
            #pragma unroll
            for (int n = 0; n < 2; ++n) acc[g][m][n] = (f32x4)0.f;

    for (int k0 = 0; k0 < CD; k0 += 64) {
        #pragma unroll
        for (int it = 0; it < 2; ++it) {
            int arow = bm + it * 32 + srow; if (arow >= NN) arow = NN - 1;
            __builtin_amdgcn_global_load_lds(
                (const __attribute__((address_space(1))) void*)&ag[(size_t)arow * CD + k0 + skc],
                (__attribute__((address_space(3))) void*)((char*)Aag + it * 4096 + tid * 16),
                16, 0, 0);
            __builtin_amdgcn_global_load_lds(
                (const __attribute__((address_space(1))) void*)&g0[(size_t)arow * CD + k0 + skc],
                (__attribute__((address_space(3))) void*)((char*)Ag0 + it * 4096 + tid * 16),
                16, 0, 0);
        }
        #pragma unroll
        for (int p = 0; p < 3; ++p) {
            #pragma unroll
            for (int hf = 0; hf < 2; ++hf) {
                int grow = p * 256 + jb + hf * 32 + srow;
                __builtin_amdgcn_global_load_lds(
                    (const __attribute__((address_space(1))) void*)&Bc[(size_t)grow * CD + k0 + skc],
                    (__attribute__((address_space(3))) void*)((char*)SBc + p * 8192 + hf * 4096 + tid * 16),
                    16, 0, 0);
                __builtin_amdgcn_global_load_lds(
                    (const __attribute__((address_space(1))) void*)&whh[(size_t)grow * CD + k0 + skc],
                    (__attribute__((address_space(3))) void*)((char*)SWh + p * 8192 + hf * 4096 + tid * 16),
                    16, 0, 0);
            }
        }
        __syncthreads();

        #pragma unroll
        for (int ks = 0; ks < 2; ++ks) {
            const int col = (ks * 32 + kg) ^ rsw;
            f16x8 aa[2], gg[2];
            #pragma unroll
            for (int m = 0; m < 2; ++m) {
                int arl = (wrow * 32 + m * 16 + fr) * 64 + col;
                aa[m] = *(const f16x8*)&Aag[arl];
                gg[m] = *(const f16x8*)&Ag0[arl];
            }
            #pragma unroll
            for (int p = 0; p < 3; ++p) {
                #pragma unroll
                for (int n = 0; n < 2; ++n) {
                    int brl = p * 4096 + (wcol * 32 + n * 16 + fr) * 64 + col;
                    f16x8 bc = *(const f16x8*)&SBc[brl];
                    f16x8 bw = *(const f16x8*)&SWh[brl];
                    #pragma unroll
                    for (int m = 0; m < 2; ++m) {
                        acc[p][m][n]     = __builtin_amdgcn_mfma_f32_16x16x32_f16(aa[m], bc, acc[p][m][n], 0, 0, 0);
                        acc[3 + p][m][n] = __builtin_amdgcn_mfma_f32_16x16x32_f16(gg[m], bw, acc[3 + p][m][n], 0, 0, 0);
                    }
                }
            }
        }
        __syncthreads();
    }

    float bI[3][2], bH[3][2];
    #pragma unroll
    for (int p = 0; p < 3; ++p)
        #pragma unroll
        for (int n = 0; n < 2; ++n) {
            int gc = p * 256 + jb + wcol * 32 + n * 16 + fr;
            bI[p][n] = bih[gc];
            bH[p][n] = bhh[gc];
        }

    #pragma unroll
    for (int m = 0; m < 2; ++m) {
        const int rb = bm + wrow * 32 + m * 16;   // wave-uniform window
        #pragma unroll
        for (int n = 0; n < 2; ++n) {
            int col = jb + wcol * 32 + n * 16 + fr;
            float gv[4];
            #pragma unroll
            for (int jj = 0; jj < 4; ++jj) {
                gv[jj] = 0.f;
                int row = rb + fq * 4 + jj;
                if (row >= NN) continue;
                float Ir = acc[0][m][n][jj] + bI[0][n];
                float Iz = acc[1][m][n][jj] + bI[1][n];
                float In = acc[2][m][n][jj] + bI[2][n];
                float Hr = acc[3][m][n][jj] + bH[0][n];
                float Hz = acc[4][m][n][jj] + bH[1][n];
                float Hn = acc[5][m][n][jj] + bH[2][n];
                float rr = 1.f / (1.f + expf(-(Ir + Hr)));
                float zz = 1.f / (1.f + expf(-(Iz + Hz)));
                float nv = tanhf(In + rr * Hn);
                float ho = h2f(g0[(size_t)row * CD + col]);
                float res = (1.f - zz) * nv + zz * ho;
                if (!STATS) {
                    g1[(size_t)row * CD + col] = f2h(res);
                } else {
                    float val = 0.5f * res * (1.f + erff(res * 0.70710678118654752f));
                    mout[(size_t)row * CD + col] = f2h(val);
                    gv[jj] = val;
                }
            }
            if (STATS) {
                bool uni = (rb + 15 < NN) && (batch[rb] == batch[rb + 15]);
                if (uni) {
                    float s = gv[0] + gv[1] + gv[2] + gv[3];
                    float qq = gv[0]*gv[0] + gv[1]*gv[1] + gv[2]*gv[2] + gv[3]*gv[3];
                    s  += __shfl_xor(s, 16);  s  += __shfl_xor(s, 32);
                    qq += __shfl_xor(qq, 16); qq += __shfl_xor(qq, 32);
                    if (fq == 0) {
                        int gb2 = batch[rb];
                        atomicAdd(&sums [gb2 * CD + col], s);
                        atomicAdd(&sumsq[gb2 * CD + col], qq);
                    }
                } else {
                    int run = -1; float s = 0.f, qq = 0.f;
                    #pragma unroll
                    for (int jj = 0; jj < 4; ++jj) {
                        int row = rb + fq * 4 + jj;
                        if (row >= NN) break;
                        int gb2 = batch[row];
                        if (gb2 != run) {
                            if (run >= 0) {
                                atomicAdd(&sums [run * CD + col], s);
                                atomicAdd(&sumsq[run * CD + col], qq);
                            }
                            run = gb2; s = 0.f; qq = 0.f;
                        }
                        s += gv[jj]; qq += gv[jj] * gv[jj];
                    }
                    if (run >= 0) {
                        atomicAdd(&sums [run * CD + col], s);
                        atomicAdd(&sumsq[run * CD + col], qq);
                    }
                }
            }
        }
    }
}

// ---------------------------------------------------------------------------
// Edge aggregation: WAVE-per-node, register-only, 16B/lane (u16x8).
// CHN=256: 32 lanes/node, 2 nodes/wave.  CHN=128: 16 lanes/node, 4 nodes/wave.
// ---------------------------------------------------------------------------
template<int CHN, bool GCN>
__global__ __launch_bounds__(256) void agg_kernel(const u16* __restrict__ feat,
                                                  const int* __restrict__ offsets,
                                                  const int* __restrict__ srcs,
                                                  const float* __restrict__ wts,
                                                  const float* __restrict__ dinv,
                                                  u16* __restrict__ outp) {
    constexpr int LPN = CHN / 8;       // lanes per node
    constexpr int NPW = 64 / LPN;      // nodes per wave
    constexpr int NPB = 4 * NPW;       // nodes per block
    const int lane = threadIdx.x & 63;
    const int wave = threadIdx.x >> 6;
    const int sub  = lane / LPN;
    const int ln   = lane % LPN;
    const int v = blockIdx.x * NPB + wave * NPW + sub;
    if (v >= NN) return;

    const int o0 = offsets[v], o1 = offsets[v + 1];
    float a[8];
    #pragma unroll
    for (int t = 0; t < 8; ++t) a[t] = 0.f;
    int o = o0;
    for (; o + 4 <= o1; o += 4) {
        int s0 = srcs[o], s1 = srcs[o + 1], s2 = srcs[o + 2], s3 = srcs[o + 3];
        u16x8 m0 = *(const u16x8*)&feat[(size_t)s0 * CHN + ln * 8];
        u16x8 m1 = *(const u16x8*)&feat[(size_t)s1 * CHN + ln * 8];
        u16x8 m2 = *(const u16x8*)&feat[(size_t)s2 * CHN + ln * 8];
        u16x8 m3 = *(const u16x8*)&feat[(size_t)s3 * CHN + ln * 8];
        float w0 = GCN ? wts[o]     : 1.f;
        float w1 = GCN ? wts[o + 1] : 1.f;
        float w2 = GCN ? wts[o + 2] : 1.f;
        float w3 = GCN ? wts[o + 3] : 1.f;
        #pragma unroll
        for (int t = 0; t < 8; ++t)
            a[t] += w0 * h2f(m0[t]) + w1 * h2f(m1[t]) + w2 * h2f(m2[t]) + w3 * h2f(m3[t]);
    }
    for (; o < o1; ++o) {
        int s = srcs[o];
        float w = GCN ? wts[o] : 1.f;
        u16x8 mv = *(const u16x8*)&feat[(size_t)s * CHN + ln * 8];
        #pragma unroll
        for (int t = 0; t < 8; ++t) a[t] += w * h2f(mv[t]);
    }
    if (GCN) {
        float dv = dinv[v];
        u16x8 sv = *(const u16x8*)&feat[(size_t)v * CHN + ln * 8];
        #pragma unroll
        for (int t = 0; t < 8; ++t) a[t] = dv * a[t] + dv * dv * h2f(sv[t]);
    }
    u16x8 ov;
    #pragma unroll
    for (int t = 0; t < 8; ++t) ov[t] = f2h(a[t]);
    *(u16x8*)&outp[(size_t)v * CHN + ln * 8] = ov;
}

// ---------------------------------------------------------------------------
// GN apply with inline finalize; writes h_h only (post-norm state == residual).
// ---------------------------------------------------------------------------
template<bool RES>
__global__ void gn_apply_kernel(const u16* __restrict__ x,
                                const int* __restrict__ batch,
                                const float* __restrict__ sums,
                                const float* __restrict__ sumsq,
                                const int* __restrict__ cntg,
                                const float* __restrict__ w,
                                const float* __restrict__ ms,
                                const float* __restrict__ bvec,
                                u16* __restrict__ h_h) {
    int i = blockIdx.x * blockDim.x + threadIdx.x;   // over NN*64
    if (i >= NN * (CD / 4)) return;
    int v = i >> 6, c4 = (i & 63) << 2;
    int gb = batch[v];
    size_t idx = (size_t)v * CD + c4;
    ushort4 xv = *(const ushort4*)&x[idx];
    float4 sm = *(const float4*)&sums[gb * CD + c4];
    float4 sq = *(const float4*)&sumsq[gb * CD + c4];
    float4 wv = *(const float4*)&w[c4];
    float4 mv = *(const float4*)&ms[c4];
    float4 bb = *(const float4*)&bvec[c4];
    float rc = 1.0f / fmaxf((float)cntg[gb], 1.0f);
    float4 val;
    #pragma unroll
    for (int t = 0; t < 4; ++t) {
        float mean = (&sm.x)[t] * rc;
        float ex2  = (&sq.x)[t] * rc;
        float msm  = (&mv.x)[t] * mean;
        float var  = ex2 - 2.f * msm * mean + msm * msm;
        float scale = (&wv.x)[t] * rsqrtf(var + EPSV);
        (&val.x)[t] = (h2f((&xv.x)[t]) - msm) * scale + (&bb.x)[t];
    }
    if (RES) {
        ushort4 hv = *(const ushort4*)&h_h[idx];
        val.x += h2f(hv.x); val.y += h2f(hv.y); val.z += h2f(hv.z); val.w += h2f(hv.w);
    }
    ushort4 ov; ov.x = f2h(val.x); ov.y = f2h(val.y); ov.z = f2h(val.z); ov.w = f2h(val.w);
    *(ushort4*)&h_h[idx] = ov;
}

// ---------------------------------------------------------------------------
// Host
// ---------------------------------------------------------------------------
extern "C" void kernel_launch(void* const* d_in, const int* in_sizes, int n_in,
                              void* d_out, int out_size, void* d_ws, size_t ws_size,
                              hipStream_t stream) {
    const float* x      = (const float*)d_in[0];
    const int*   ei     = (const int*)d_in[1];
    const int*   batch  = (const int*)d_in[2];
    const float* gcn_w  = (const float*)d_in[3];
    const float* gcn_b  = (const float*)d_in[4];
    const float* gn0_w  = (const float*)d_in[5];
    const float* gn0_b  = (const float*)d_in[6];
    const float* gn0_ms = (const float*)d_in[7];
    const float* ggc_w  = (const float*)d_in[8];
    const float* gru_wih = (const float*)d_in[9];
    const float* gru_whh = (const float*)d_in[10];
    const float* gru_bih = (const float*)d_in[11];
    const float* gru_bhh = (const float*)d_in[12];
    const float* gn_w   = (const float*)d_in[13];
    const float* gn_b   = (const float*)d_in[14];
    const float* gn_ms  = (const float*)d_in[15];
    const float* lin_w  = (const float*)d_in[16];
    const float* lin_b  = (const float*)d_in[17];
    float* outp = (float*)d_out;

    const int* srcv = ei;
    const int* dstv = ei + EE;

    char* base = (char*)d_ws;
    size_t off = 0;
    auto alloc = [&](size_t bytes) -> void* {
        void* p = base + off;
        off = (off + bytes + 255) & ~(size_t)255;
        return p;
    };

    // ---- zeroed-at-start region ----
    int*   counts   = (int*)alloc(NN * 4);
    int*   cursor   = (int*)alloc(NN * 4);
    int*   cntg     = (int*)alloc(GG * 4);
    float* sums_all = (float*)alloc((size_t)4 * 2 * GG * CD * 4);  // 4 stages x (sums,sumsq)
    size_t zero_end = off;

    int*   offsets = (int*)alloc((NN + 1) * 4);
    int*   srcs    = (int*)alloc((size_t)EE * 4);
    float* wts     = (float*)alloc((size_t)EE * 4);
    float* dinv    = (float*)alloc(NN * 4);
    // f16 weights
    u16* gcn_wt = (u16*)alloc((size_t)CD * IND * 2);
    u16* ggc_h  = (u16*)alloc((size_t)6 * CD * CD * 2);
    u16* wih_h  = (u16*)alloc((size_t)LL * 3 * CD * CD * 2);
    u16* whh_h  = (u16*)alloc((size_t)LL * 3 * CD * CD * 2);
    u16* lin_wt = (u16*)alloc((size_t)OUTD * CD * 2);
    u16* Bc     = (u16*)alloc((size_t)6 * 3 * CD * CD * 2);
    // activations (all f16)
    u16* x_h  = (u16*)alloc((size_t)NN * IND * 2);
    u16* ax_h = (u16*)alloc((size_t)NN * IND * 2);
    u16* gmid = (u16*)alloc((size_t)NN * CD * 2);
    u16* h_h  = (u16*)alloc((size_t)NN * CD * 2);
    u16* m_h  = (u16*)alloc((size_t)NN * CD * 2);
    u16* a_h  = (u16*)alloc((size_t)NN * CD * 2);

    // ---- CSR build + per-graph counts ----
    hipMemsetAsync(counts, 0, zero_end, stream);
    hist_kernel<<<512, 256, 0, stream>>>(dstv, batch, counts, cntg);
    scan_kernel<<<1, 1024, 0, stream>>>(counts, offsets, dinv);
    fill_kernel<<<(EE + 255) / 256, 256, 0, stream>>>(srcv, dstv, offsets, cursor, dinv, srcs, wts);

    // ---- fused conversions (x + all weights) ----
    {
        const int tot4 = NN * IND / 4 + CD * IND / 4 + 6 * CD * CD / 4
                       + 2 * (LL * 3 * CD * CD / 4) + OUTD * CD / 4;
        conv_all_kernel<<<(tot4 + 255) / 256, 256, 0, stream>>>(
            x, gcn_w, ggc_w, gru_wih, gru_whh, lin_w,
            x_h, gcn_wt, ggc_h, wih_h, whh_h, lin_wt);
    }

    // ---- all 6 Bc = wih @ ggc^T in one launch ----
    gemm_bc_kernel<<<72, 256, 0, stream>>>(wih_h, ggc_h, Bc);

    const int gmx = (NN + 127) / 128;      // 157
    const int nv4 = (NN * (CD / 4) + 255) / 256;
    const int nfused = ((NN + 63) / 64) * 4;  // 1252
    const int nagg256 = (NN + 7) / 8;      // 8 nodes/block (2/wave)
    const int nagg128 = (NN + 15) / 16;    // 16 nodes/block (4/wave)

    // ---- GCNConv: aggregate x (128ch), then GEMM with fused stage-0 stats ----
    float* sums0  = sums_all;
    float* sumsq0 = sums0 + GG * CD;
    agg_kernel<IND, true><<<nagg128, 256, 0, stream>>>(x_h, offsets, srcs, wts, dinv, ax_h);
    gemm_mfma<true, true, true><<<dim3(gmx, CD / 128), 256, 0, stream>>>(
        ax_h, gcn_wt, gcn_b, nullptr, a_h, NN, CD, IND, batch, sums0, sumsq0);
    gn_apply_kernel<false><<<nv4, 256, 0, stream>>>(a_h, batch, sums0, sumsq0, cntg,
                                                    gn0_w, gn0_ms, gn0_b, h_h);

    // ---- gated blocks (state lives in h_h after each norm) ----
    for (int l = 0; l < LL; ++l) {
        const u16* whh = whh_h + (size_t)l * 3 * CD * CD;
        const float* bih = gru_bih + (size_t)l * 3 * CD;
        const float* bhh = gru_bhh + (size_t)l * 3 * CD;
        float* sums  = sums_all + (size_t)(1 + l) * 2 * GG * CD;
        float* sumsq = sums + GG * CD;
        const u16* Bc0 = Bc + ((size_t)l * 2 + 0) * 3 * CD * CD;
        const u16* Bc1 = Bc + ((size_t)l * 2 + 1) * 3 * CD * CD;

        // i = 0: state h_h -> gmid
        agg_kernel<CD, false><<<nagg256, 256, 0, stream>>>(h_h, offsets, srcs, wts, dinv, a_h);
        fused_gate_gru_kernel<false><<<nfused, 256, 0, stream>>>(
            a_h, h_h, Bc0, whh, bih, bhh, gmid, nullptr, nullptr, nullptr, nullptr);
        // i = 1: state gmid -> (gelu m_h + stats); raw state dead
        agg_kernel<CD, false><<<nagg256, 256, 0, stream>>>(gmid, offsets, srcs, wts, dinv, a_h);
        fused_gate_gru_kernel<true><<<nfused, 256, 0, stream>>>(
            a_h, gmid, Bc1, whh, bih, bhh, nullptr, batch, m_h, sums, sumsq);

        gn_apply_kernel<true><<<nv4, 256, 0, stream>>>(m_h, batch, sums, sumsq, cntg,
                                                       gn_w + l * CD, gn_ms + l * CD, gn_b + l * CD, h_h);
    }

    // ---- final linear on f16 h ----
    gemm_mfma<true, false, false><<<dim3(gmx, OUTD / 128), 256, 0, stream>>>(
        h_h, lin_wt, lin_b, outp, nullptr, NN, OUTD, CD, nullptr, nullptr, nullptr);
}

// Round 20
// 529.208 us; speedup vs baseline: 1.3770x; 1.1085x over previous
//
#include <hip/hip_runtime.h>
#include <math.h>

typedef unsigned short u16;
typedef _Float16 f16;
typedef __attribute__((ext_vector_type(8))) _Float16 f16x8;
typedef __attribute__((ext_vector_type(4))) float f32x4;
typedef __attribute__((ext_vector_type(8))) unsigned short u16x8;

constexpr int NN   = 20000;
constexpr int EE   = 320000;
constexpr int CD   = 256;
constexpr int IND  = 128;
constexpr int OUTD = 128;
constexpr int LL   = 3;
constexpr int GG   = 16;
constexpr float EPSV = 1e-5f;

__device__ __forceinline__ u16 f2h(float f) {
    union { f16 h; u16 u; } v; v.h = (f16)f; return v.u;
}
__device__ __forceinline__ float h2f(u16 u) {
    union { u16 u; f16 h; } v; v.u = u; return (float)v.h;
}
// fast transcendentals via v_exp_f32 / v_rcp_f32.
// ftanh uses the saturating |x| form: t = exp(-2|x|) in (0,1] -- NO overflow
// (round-19 bug: t = exp(-2x) -> inf for x<<0 -> (1-inf)*0 = NaN).
__device__ __forceinline__ float frcp(float x) { return __builtin_amdgcn_rcpf(x); }
__device__ __forceinline__ float fsig(float x) { return frcp(1.f + __expf(-x)); }
__device__ __forceinline__ float ftanh(float x) {
    float t = __expf(-2.f * fabsf(x));
    float r = (1.f - t) * frcp(1.f + t);
    return copysignf(r, x);
}
__device__ __forceinline__ float fgelu(float x) {
    float u = 0.7978845608028654f * (x + 0.044715f * x * x * x);
    return 0.5f * x * (1.f + ftanh(u));
}

// ---------------------------------------------------------------------------
// CSR build: fused edge histogram + batch histogram
// ---------------------------------------------------------------------------
__global__ void hist_kernel(const int* __restrict__ dst, const int* __restrict__ batch,
                            int* __restrict__ counts, int* __restrict__ cntg) {
    __shared__ int loc[GG];
    if (threadIdx.x < GG) loc[threadIdx.x] = 0;
    __syncthreads();
    int stride = gridDim.x * blockDim.x;
    for (int e = blockIdx.x * blockDim.x + threadIdx.x; e < EE; e += stride)
        atomicAdd(&counts[dst[e]], 1);
    for (int i = blockIdx.x * blockDim.x + threadIdx.x; i < NN; i += stride)
        atomicAdd(&loc[batch[i]], 1);
    __syncthreads();
    if (threadIdx.x < GG) atomicAdd(&cntg[threadIdx.x], loc[threadIdx.x]);
}

__global__ __launch_bounds__(1024) void scan_kernel(const int* __restrict__ counts,
                                                    int* __restrict__ offsets,
                                                    float* __restrict__ dinv) {
    __shared__ int ls[1024];
    int t = threadIdx.x;
    const int CHK = (NN + 1023) / 1024;
    int begin = t * CHK;
    int end   = begin + CHK; if (end > NN) end = NN;
    int s = 0;
    for (int i = begin; i < end && i < NN; ++i) s += counts[i];
    ls[t] = s;
    __syncthreads();
    for (int off = 1; off < 1024; off <<= 1) {
        int v = (t >= off) ? ls[t - off] : 0;
        __syncthreads();
        ls[t] += v;
        __syncthreads();
    }
    int run = ls[t] - s;
    for (int i = begin; i < end && i < NN; ++i) {
        offsets[i] = run;
        int c = counts[i];
        run += c;
        dinv[i] = rsqrtf((float)(c + 1));
    }
    if (t == 1023) offsets[NN] = run;
}

__global__ void fill_kernel(const int* __restrict__ src, const int* __restrict__ dst,
                            const int* __restrict__ offsets, int* __restrict__ cursor,
                            const float* __restrict__ dinv,
                            int* __restrict__ srcs, float* __restrict__ wts) {
    int e = blockIdx.x * blockDim.x + threadIdx.x;
    if (e >= EE) return;
    int d = dst[e];
    int p = atomicAdd(&cursor[d], 1);
    int pos = offsets[d] + p;
    int s = src[e];
    srcs[pos] = s;
    wts[pos]  = dinv[s];
}

// ---------------------------------------------------------------------------
// Fused f32 -> f16 conversion of x + all weights (one launch)
// ---------------------------------------------------------------------------
__global__ void conv_all_kernel(const float* __restrict__ x,   const float* __restrict__ gcn_w,
                                const float* __restrict__ ggc, const float* __restrict__ wih,
                                const float* __restrict__ whh, const float* __restrict__ lin,
                                u16* __restrict__ x_h,  u16* __restrict__ gcn_h,
                                u16* __restrict__ ggc_h, u16* __restrict__ wih_h,
                                u16* __restrict__ whh_h, u16* __restrict__ lin_h) {
    const int b0 = NN * IND / 4;
    const int b1 = b0 + CD * IND / 4;
    const int b2 = b1 + 6 * CD * CD / 4;
    const int b3 = b2 + LL * 3 * CD * CD / 4;
    const int b4 = b3 + LL * 3 * CD * CD / 4;
    const int b5 = b4 + OUTD * CD / 4;
    int i = blockIdx.x * blockDim.x + threadIdx.x;
    if (i >= b5) return;
    const float* src; u16* dst; int base;
    if (i < b0)      { src = x;     dst = x_h;   base = 0;  }
    else if (i < b1) { src = gcn_w; dst = gcn_h; base = b0; }
    else if (i < b2) { src = ggc;   dst = ggc_h; base = b1; }
    else if (i < b3) { src = wih;   dst = wih_h; base = b2; }
    else if (i < b4) { src = whh;   dst = whh_h; base = b3; }
    else             { src = lin;   dst = lin_h; base = b4; }
    int j = i - base;
    float4 v = ((const float4*)src)[j];
    ushort4 o;
    o.x = f2h(v.x); o.y = f2h(v.y); o.z = f2h(v.z); o.w = f2h(v.w);
    ((ushort4*)dst)[j] = o;
}

// ---------------------------------------------------------------------------
// f16 MFMA GEMM tile body: C[M,N] = A[M,K] * B^T (B stored [N,K]) (+bias)
// 128x128 tile, BK=64, 4 waves, global_load_lds w16, XOR-swizzled LDS (T2).
// STATS: also accumulate per-(graph,col) sums/sumsq of the f32 outputs.
// ---------------------------------------------------------------------------
template<bool BIAS, bool OUTH, bool STATS>
__device__ __forceinline__ void gemm_tile(const u16* __restrict__ A,
                                          const u16* __restrict__ B,
                                          const float* __restrict__ bias,
                                          float* __restrict__ Cf,
                                          u16* __restrict__ Ch,
                                          int M, int N, int K,
                                          int bm, int bn,
                                          u16* As, u16* Bs,
                                          const int* __restrict__ batch,
                                          float* __restrict__ sums,
                                          float* __restrict__ sumsq) {
    const int tid  = threadIdx.x;
    const int lane = tid & 63;
    const int wave = tid >> 6;
    const int wr = wave >> 1, wc = wave & 1;

    f32x4 acc[4][4];
    #pragma unroll
    for (int i = 0; i < 4; ++i)
        #pragma unroll
        for (int j = 0; j < 4; ++j) acc[i][j] = (f32x4)0.f;

    const int srow = tid >> 3;                              // 0..31
    const int skc  = ((tid & 7) * 8) ^ ((srow & 7) << 3);   // swizzled source k-offset

    const int fr = lane & 15;
    const int kg = (lane >> 4) * 8;
    const int rsw = (fr & 7) << 3;

    for (int k0 = 0; k0 < K; k0 += 64) {
        #pragma unroll
        for (int it = 0; it < 4; ++it) {
            int row  = srow + it * 32;
            int arow = bm + row; if (arow >= M) arow = M - 1;
            const u16* ga = &A[(size_t)arow * K + k0 + skc];
            const u16* gb = &B[(size_t)(bn + row) * K + k0 + skc];
            __builtin_amdgcn_global_load_lds(
                (const __attribute__((address_space(1))) void*)ga,
                (__attribute__((address_space(3))) void*)((char*)As + it * 4096 + tid * 16),
                16, 0, 0);
            __builtin_amdgcn_global_load_lds(
                (const __attribute__((address_space(1))) void*)gb,
                (__attribute__((address_space(3))) void*)((char*)Bs + it * 4096 + tid * 16),
                16, 0, 0);
        }
        __syncthreads();

        #pragma unroll
        for (int ks = 0; ks < 2; ++ks) {
            const int col = (ks * 32 + kg) ^ rsw;
            f16x8 af[4], bfr[4];
            #pragma unroll
            for (int m2 = 0; m2 < 4; ++m2)
                af[m2] = *(const f16x8*)&As[(wr * 64 + m2 * 16 + fr) * 64 + col];
            #pragma unroll
            for (int n2 = 0; n2 < 4; ++n2)
                bfr[n2] = *(const f16x8*)&Bs[(wc * 64 + n2 * 16 + fr) * 64 + col];
            #pragma unroll
            for (int m2 = 0; m2 < 4; ++m2)
                #pragma unroll
                for (int n2 = 0; n2 < 4; ++n2)
                    acc[m2][n2] = __builtin_amdgcn_mfma_f32_16x16x32_f16(af[m2], bfr[n2], acc[m2][n2], 0, 0, 0);
        }
        __syncthreads();
    }

    const int fq = lane >> 4;
    float bv[4];
    if (BIAS) {
        #pragma unroll
        for (int n2 = 0; n2 < 4; ++n2) bv[n2] = bias[bn + wc * 64 + n2 * 16 + fr];
    }
    #pragma unroll
    for (int m2 = 0; m2 < 4; ++m2) {
        const int rb = bm + wr * 64 + m2 * 16;   // wave-uniform 16-row window
        #pragma unroll
        for (int n2 = 0; n2 < 4; ++n2) {
            int col = bn + wc * 64 + n2 * 16 + fr;
            float gv[4];
            #pragma unroll
            for (int j = 0; j < 4; ++j) {
                gv[j] = 0.f;
                int r = rb + fq * 4 + j;
                if (r < M) {
                    float v = acc[m2][n2][j];
                    if (BIAS) v += bv[n2];
                    if (OUTH) Ch[(size_t)r * N + col] = f2h(v);
                    else      Cf[(size_t)r * N + col] = v;
                    if (STATS) gv[j] = v;
                }
            }
            if (STATS) {
                bool uni = (rb + 15 < M) && (batch[rb] == batch[rb + 15]);
                if (uni) {
                    float s = gv[0] + gv[1] + gv[2] + gv[3];
                    float qq = gv[0]*gv[0] + gv[1]*gv[1] + gv[2]*gv[2] + gv[3]*gv[3];
                    s  += __shfl_xor(s, 16);  s  += __shfl_xor(s, 32);
                    qq += __shfl_xor(qq, 16); qq += __shfl_xor(qq, 32);
                    if (fq == 0) {
                        int gb2 = batch[rb];
                        atomicAdd(&sums [gb2 * CD + col], s);
                        atomicAdd(&sumsq[gb2 * CD + col], qq);
                    }
                } else {
                    int run = -1; float s = 0.f, qq = 0.f;
                    #pragma unroll
                    for (int j = 0; j < 4; ++j) {
                        int r = rb + fq * 4 + j;
                        if (r >= M) break;
                        int gb2 = batch[r];
                        if (gb2 != run) {
                            if (run >= 0) {
                                atomicAdd(&sums [run * CD + col], s);
                                atomicAdd(&sumsq[run * CD + col], qq);
                            }
                            run = gb2; s = 0.f; qq = 0.f;
                        }
                        s += gv[j]; qq += gv[j] * gv[j];
                    }
                    if (run >= 0) {
                        atomicAdd(&sums [run * CD + col], s);
                        atomicAdd(&sumsq[run * CD + col], qq);
                    }
                }
            }
        }
    }
}

template<bool BIAS, bool OUTH, bool STATS>
__global__ __launch_bounds__(256) void gemm_mfma(const u16* __restrict__ A,
                                                 const u16* __restrict__ B,
                                                 const float* __restrict__ bias,
                                                 float* __restrict__ Cf,
                                                 u16* __restrict__ Ch,
                                                 int M, int N, int K,
                                                 const int* __restrict__ batch,
                                                 float* __restrict__ sums,
                                                 float* __restrict__ sumsq) {
    __shared__ u16 As[128 * 64];
    __shared__ u16 Bs[128 * 64];
    gemm_tile<BIAS, OUTH, STATS>(A, B, bias, Cf, Ch, M, N, K,
                                 blockIdx.x * 128, blockIdx.y * 128, As, Bs,
                                 batch, sums, sumsq);
}

// All 6 Bc = wih_l @ ggc[l,i]^T  (768x256 each) in ONE launch: 72 blocks
__global__ __launch_bounds__(256) void gemm_bc_kernel(const u16* __restrict__ wih_h,
                                                      const u16* __restrict__ ggc_h,
                                                      u16* __restrict__ Bc) {
    __shared__ u16 As[128 * 64];
    __shared__ u16 Bs[128 * 64];
    int b = blockIdx.x;            // 0..71
    int mat = b / 12, rem = b % 12;
    int bx = rem % 6, by = rem / 6;
    gemm_tile<false, true, false>(wih_h + (size_t)(mat >> 1) * 3 * CD * CD,
                                  ggc_h + (size_t)mat * CD * CD,
                                  nullptr, nullptr,
                                  Bc + (size_t)mat * 3 * CD * CD,
                                  3 * CD, CD, CD, bx * 128, by * 128, As, Bs,
                                  nullptr, nullptr, nullptr);
}

// ---------------------------------------------------------------------------
// FUSED gate-GEMM + GRU (v4 structure) + optional STATS epilogue.
// Fast transcendentals (fsig/ftanh/fgelu, saturating forms).
// ---------------------------------------------------------------------------
template<bool STATS>
__global__ __launch_bounds__(256) void fused_gate_gru_kernel(
        const u16* __restrict__ ag,    // agg(g0) [NN][256]
        const u16* __restrict__ g0,    // current state [NN][256]
        const u16* __restrict__ Bc,    // combined wih@W^T [768][256]
        const u16* __restrict__ whh,   // [768][256]
        const float* __restrict__ bih, // [768]
        const float* __restrict__ bhh, // [768]
        u16* __restrict__ g1,          // new state out (!STATS)
        const int* __restrict__ batch, // [NN] (STATS)
        u16* __restrict__ mout,        // gelu out (STATS)
        float* __restrict__ sums,      // [GG][CD] (STATS)
        float* __restrict__ sumsq) {   // [GG][CD] (STATS)
    __shared__ u16 S[32768];           // 64 KB
    u16* Aag = S;                      // 64x64
    u16* Ag0 = S + 4096;               // 64x64
    u16* SBc = S + 8192;               // 192x64
    u16* SWh = S + 20480;              // 192x64

    const int nwg = gridDim.x;         // 1252
    const int q = nwg >> 3, r = nwg & 7;
    int xcd = blockIdx.x & 7, idx = blockIdx.x >> 3;
    int nid = (xcd < r ? xcd * (q + 1) : r * (q + 1) + (xcd - r) * q) + idx;
    const int bm = (nid >> 2) * 64;    // row base
    const int jb = (nid & 3) * 64;     // gru-col base

    const int tid  = threadIdx.x;
    const int lane = tid & 63;
    const int wave = tid >> 6;         // 0..3
    const int wrow = wave >> 1;
    const int wcol = wave & 1;
    const int fr = lane & 15;
    const int fq = lane >> 4;
    const int kg = fq * 8;
    const int rsw = (fr & 7) << 3;

    const int srow = tid >> 3;                              // 0..31
    const int skc  = ((tid & 7) * 8) ^ ((srow & 7) << 3);   // swizzled src k-off

    f32x4 acc[6][2][2];
    #pragma unroll
    for (int g = 0; g < 6; ++g)
        #pragma unroll
        for (int m = 0; m < 2; ++m)
            #pragma unroll
            for (int n = 0; n < 2; ++n) acc[g][m][n] = (f32x4)0.f;

    for (int k0 = 0; k0 < CD; k0 += 64) {
        #pragma unroll
        for (int it = 0; it < 2; ++it) {
            int arow = bm + it * 32 + srow; if (arow >= NN) arow = NN - 1;
            __builtin_amdgcn_global_load_lds(
                (const __attribute__((address_space(1))) void*)&ag[(size_t)arow * CD + k0 + skc],
                (__attribute__((address_space(3))) void*)((char*)Aag + it * 4096 + tid * 16),
                16, 0, 0);
            __builtin_amdgcn_global_load_lds(
                (const __attribute__((address_space(1))) void*)&g0[(size_t)arow * CD + k0 + skc],
                (__attribute__((address_space(3))) void*)((char*)Ag0 + it * 4096 + tid * 16),
                16, 0, 0);
        }
        #pragma unroll
        for (int p = 0; p < 3; ++p) {
            #pragma unroll
            for (int hf = 0; hf < 2; ++hf) {
                int grow = p * 256 + jb + hf * 32 + srow;
                __builtin_amdgcn_global_load_lds(
                    (const __attribute__((address_space(1))) void*)&Bc[(size_t)grow * CD + k0 + skc],
                    (__attribute__((address_space(3))) void*)((char*)SBc + p * 8192 + hf * 4096 + tid * 16),
                    16, 0, 0);
                __builtin_amdgcn_global_load_lds(
                    (const __attribute__((address_space(1))) void*)&whh[(size_t)grow * CD + k0 + skc],
                    (__attribute__((address_space(3))) void*)((char*)SWh + p * 8192 + hf * 4096 + tid * 16),
                    16, 0, 0);
            }
        }
        __syncthreads();

        #pragma unroll
        for (int ks = 0; ks < 2; ++ks) {
            const int col = (ks * 32 + kg) ^ rsw;
            f16x8 aa[2], gg[2];
            #pragma unroll
            for (int m = 0; m < 2; ++m) {
                int arl = (wrow * 32 + m * 16 + fr) * 64 + col;
                aa[m] = *(const f16x8*)&Aag[arl];
                gg[m] = *(const f16x8*)&Ag0[arl];
            }
            #pragma unroll
            for (int p = 0; p < 3; ++p) {
                #pragma unroll
                for (int n = 0; n < 2; ++n) {
                    int brl = p * 4096 + (wcol * 32 + n * 16 + fr) * 64 + col;
                    f16x8 bc = *(const f16x8*)&SBc[brl];
                    f16x8 bw = *(const f16x8*)&SWh[brl];
                    #pragma unroll
                    for (int m = 0; m < 2; ++m) {
                        acc[p][m][n]     = __builtin_amdgcn_mfma_f32_16x16x32_f16(aa[m], bc, acc[p][m][n], 0, 0, 0);
                        acc[3 + p][m][n] = __builtin_amdgcn_mfma_f32_16x16x32_f16(gg[m], bw, acc[3 + p][m][n], 0, 0, 0);
                    }
                }
            }
        }
        __syncthreads();
    }

    float bI[3][2], bH[3][2];
    #pragma unroll
    for (int p = 0; p < 3; ++p)
        #pragma unroll
        for (int n = 0; n < 2; ++n) {
            int gc = p * 256 + jb + wcol * 32 + n * 16 + fr;
            bI[p][n] = bih[gc];
            bH[p][n] = bhh[gc];
        }

    #pragma unroll
    for (int m = 0; m < 2; ++m) {
        const int rb = bm + wrow * 32 + m * 16;   // wave-uniform window
        #pragma unroll
        for (int n = 0; n < 2; ++n) {
            int col = jb + wcol * 32 + n * 16 + fr;
            float gv[4];
            #pragma unroll
            for (int jj = 0; jj < 4; ++jj) {
                gv[jj] = 0.f;
                int row = rb + fq * 4 + jj;
                if (row >= NN) continue;
                float Ir = acc[0][m][n][jj] + bI[0][n];
                float Iz = acc[1][m][n][jj] + bI[1][n];
                float In = acc[2][m][n][jj] + bI[2][n];
                float Hr = acc[3][m][n][jj] + bH[0][n];
                float Hz = acc[4][m][n][jj] + bH[1][n];
                float Hn = acc[5][m][n][jj] + bH[2][n];
                float rr = fsig(Ir + Hr);
                float zz = fsig(Iz + Hz);
                float nv = ftanh(In + rr * Hn);
                float ho = h2f(g0[(size_t)row * CD + col]);
                float res = (1.f - zz) * nv + zz * ho;
                if (!STATS) {
                    g1[(size_t)row * CD + col] = f2h(res);
                } else {
                    float val = fgelu(res);
                    mout[(size_t)row * CD + col] = f2h(val);
                    gv[jj] = val;
                }
            }
            if (STATS) {
                bool uni = (rb + 15 < NN) && (batch[rb] == batch[rb + 15]);
                if (uni) {
                    float s = gv[0] + gv[1] + gv[2] + gv[3];
                    float qq = gv[0]*gv[0] + gv[1]*gv[1] + gv[2]*gv[2] + gv[3]*gv[3];
                    s  += __shfl_xor(s, 16);  s  += __shfl_xor(s, 32);
                    qq += __shfl_xor(qq, 16); qq += __shfl_xor(qq, 32);
                    if (fq == 0) {
                        int gb2 = batch[rb];
                        atomicAdd(&sums [gb2 * CD + col], s);
                        atomicAdd(&sumsq[gb2 * CD + col], qq);
                    }
                } else {
                    int run = -1; float s = 0.f, qq = 0.f;
                    #pragma unroll
                    for (int jj = 0; jj < 4; ++jj) {
                        int row = rb + fq * 4 + jj;
                        if (row >= NN) break;
                        int gb2 = batch[row];
                        if (gb2 != run) {
                            if (run >= 0) {
                                atomicAdd(&sums [run * CD + col], s);
                                atomicAdd(&sumsq[run * CD + col], qq);
                            }
                            run = gb2; s = 0.f; qq = 0.f;
                        }
                        s += gv[jj]; qq += gv[jj] * gv[jj];
                    }
                    if (run >= 0) {
                        atomicAdd(&sums [run * CD + col], s);
                        atomicAdd(&sumsq[run * CD + col], qq);
                    }
                }
            }
        }
    }
}

// ---------------------------------------------------------------------------
// Edge aggregation: WAVE-per-node, register-only, 16B/lane (u16x8).
// ---------------------------------------------------------------------------
template<int CHN, bool GCN>
__global__ __launch_bounds__(256) void agg_kernel(const u16* __restrict__ feat,
                                                  const int* __restrict__ offsets,
                                                  const int* __restrict__ srcs,
                                                  const float* __restrict__ wts,
                                                  const float* __restrict__ dinv,
                                                  u16* __restrict__ outp) {
    constexpr int LPN = CHN / 8;       // lanes per node
    constexpr int NPW = 64 / LPN;      // nodes per wave
    constexpr int NPB = 4 * NPW;       // nodes per block
    const int lane = threadIdx.x & 63;
    const int wave = threadIdx.x >> 6;
    const int sub  = lane / LPN;
    const int ln   = lane % LPN;
    const int v = blockIdx.x * NPB + wave * NPW + sub;
    if (v >= NN) return;

    const int o0 = offsets[v], o1 = offsets[v + 1];
    float a[8];
    #pragma unroll
    for (int t = 0; t < 8; ++t) a[t] = 0.f;
    int o = o0;
    for (; o + 4 <= o1; o += 4) {
        int s0 = srcs[o], s1 = srcs[o + 1], s2 = srcs[o + 2], s3 = srcs[o + 3];
        u16x8 m0 = *(const u16x8*)&feat[(size_t)s0 * CHN + ln * 8];
        u16x8 m1 = *(const u16x8*)&feat[(size_t)s1 * CHN + ln * 8];
        u16x8 m2 = *(const u16x8*)&feat[(size_t)s2 * CHN + ln * 8];
        u16x8 m3 = *(const u16x8*)&feat[(size_t)s3 * CHN + ln * 8];
        float w0 = GCN ? wts[o]     : 1.f;
        float w1 = GCN ? wts[o + 1] : 1.f;
        float w2 = GCN ? wts[o + 2] : 1.f;
        float w3 = GCN ? wts[o + 3] : 1.f;
        #pragma unroll
        for (int t = 0; t < 8; ++t)
            a[t] += w0 * h2f(m0[t]) + w1 * h2f(m1[t]) + w2 * h2f(m2[t]) + w3 * h2f(m3[t]);
    }
    for (; o < o1; ++o) {
        int s = srcs[o];
        float w = GCN ? wts[o] : 1.f;
        u16x8 mv = *(const u16x8*)&feat[(size_t)s * CHN + ln * 8];
        #pragma unroll
        for (int t = 0; t < 8; ++t) a[t] += w * h2f(mv[t]);
    }
    if (GCN) {
        float dv = dinv[v];
        u16x8 sv = *(const u16x8*)&feat[(size_t)v * CHN + ln * 8];
        #pragma unroll
        for (int t = 0; t < 8; ++t) a[t] = dv * a[t] + dv * dv * h2f(sv[t]);
    }
    u16x8 ov;
    #pragma unroll
    for (int t = 0; t < 8; ++t) ov[t] = f2h(a[t]);
    *(u16x8*)&outp[(size_t)v * CHN + ln * 8] = ov;
}

// ---------------------------------------------------------------------------
// GN apply with inline finalize; writes h_h only (post-norm state == residual).
// ---------------------------------------------------------------------------
template<bool RES>
__global__ void gn_apply_kernel(const u16* __restrict__ x,
                                const int* __restrict__ batch,
                                const float* __restrict__ sums,
                                const float* __restrict__ sumsq,
                                const int* __restrict__ cntg,
                                const float* __restrict__ w,
                                const float* __restrict__ ms,
                                const float* __restrict__ bvec,
                                u16* __restrict__ h_h) {
    int i = blockIdx.x * blockDim.x + threadIdx.x;   // over NN*64
    if (i >= NN * (CD / 4)) return;
    int v = i >> 6, c4 = (i & 63) << 2;
    int gb = batch[v];
    size_t idx = (size_t)v * CD + c4;
    ushort4 xv = *(const ushort4*)&x[idx];
    float4 sm = *(const float4*)&sums[gb * CD + c4];
    float4 sq = *(const float4*)&sumsq[gb * CD + c4];
    float4 wv = *(const float4*)&w[c4];
    float4 mv = *(const float4*)&ms[c4];
    float4 bb = *(const float4*)&bvec[c4];
    float rc = 1.0f / fmaxf((float)cntg[gb], 1.0f);
    float4 val;
    #pragma unroll
    for (int t = 0; t < 4; ++t) {
        float mean = (&sm.x)[t] * rc;
        float ex2  = (&sq.x)[t] * rc;
        float msm  = (&mv.x)[t] * mean;
        float var  = ex2 - 2.f * msm * mean + msm * msm;
        float scale = (&wv.x)[t] * rsqrtf(var + EPSV);
        (&val.x)[t] = (h2f((&xv.x)[t]) - msm) * scale + (&bb.x)[t];
    }
    if (RES) {
        ushort4 hv = *(const ushort4*)&h_h[idx];
        val.x += h2f(hv.x); val.y += h2f(hv.y); val.z += h2f(hv.z); val.w += h2f(hv.w);
    }
    ushort4 ov; ov.x = f2h(val.x); ov.y = f2h(val.y); ov.z = f2h(val.z); ov.w = f2h(val.w);
    *(ushort4*)&h_h[idx] = ov;
}

// ---------------------------------------------------------------------------
// Host
// ---------------------------------------------------------------------------
extern "C" void kernel_launch(void* const* d_in, const int* in_sizes, int n_in,
                              void* d_out, int out_size, void* d_ws, size_t ws_size,
                              hipStream_t stream) {
    const float* x      = (const float*)d_in[0];
    const int*   ei     = (const int*)d_in[1];
    const int*   batch  = (const int*)d_in[2];
    const float* gcn_w  = (const float*)d_in[3];
    const float* gcn_b  = (const float*)d_in[4];
    const float* gn0_w  = (const float*)d_in[5];
    const float* gn0_b  = (const float*)d_in[6];
    const float* gn0_ms = (const float*)d_in[7];
    const float* ggc_w  = (const float*)d_in[8];
    const float* gru_wih = (const float*)d_in[9];
    const float* gru_whh = (const float*)d_in[10];
    const float* gru_bih = (const float*)d_in[11];
    const float* gru_bhh = (const float*)d_in[12];
    const float* gn_w   = (const float*)d_in[13];
    const float* gn_b   = (const float*)d_in[14];
    const float* gn_ms  = (const float*)d_in[15];
    const float* lin_w  = (const float*)d_in[16];
    const float* lin_b  = (const float*)d_in[17];
    float* outp = (float*)d_out;

    const int* srcv = ei;
    const int* dstv = ei + EE;

    char* base = (char*)d_ws;
    size_t off = 0;
    auto alloc = [&](size_t bytes) -> void* {
        void* p = base + off;
        off = (off + bytes + 255) & ~(size_t)255;
        return p;
    };

    // ---- zeroed-at-start region ----
    int*   counts   = (int*)alloc(NN * 4);
    int*   cursor   = (int*)alloc(NN * 4);
    int*   cntg     = (int*)alloc(GG * 4);
    float* sums_all = (float*)alloc((size_t)4 * 2 * GG * CD * 4);  // 4 stages x (sums,sumsq)
    size_t zero_end = off;

    int*   offsets = (int*)alloc((NN + 1) * 4);
    int*   srcs    = (int*)alloc((size_t)EE * 4);
    float* wts     = (float*)alloc((size_t)EE * 4);
    float* dinv    = (float*)alloc(NN * 4);
    // f16 weights
    u16* gcn_wt = (u16*)alloc((size_t)CD * IND * 2);
    u16* ggc_h  = (u16*)alloc((size_t)6 * CD * CD * 2);
    u16* wih_h  = (u16*)alloc((size_t)LL * 3 * CD * CD * 2);
    u16* whh_h  = (u16*)alloc((size_t)LL * 3 * CD * CD * 2);
    u16* lin_wt = (u16*)alloc((size_t)OUTD * CD * 2);
    u16* Bc     = (u16*)alloc((size_t)6 * 3 * CD * CD * 2);
    // activations (all f16)
    u16* x_h  = (u16*)alloc((size_t)NN * IND * 2);
    u16* ax_h = (u16*)alloc((size_t)NN * IND * 2);
    u16* gmid = (u16*)alloc((size_t)NN * CD * 2);
    u16* h_h  = (u16*)alloc((size_t)NN * CD * 2);
    u16* m_h  = (u16*)alloc((size_t)NN * CD * 2);
    u16* a_h  = (u16*)alloc((size_t)NN * CD * 2);

    // ---- CSR build + per-graph counts ----
    hipMemsetAsync(counts, 0, zero_end, stream);
    hist_kernel<<<512, 256, 0, stream>>>(dstv, batch, counts, cntg);
    scan_kernel<<<1, 1024, 0, stream>>>(counts, offsets, dinv);
    fill_kernel<<<(EE + 255) / 256, 256, 0, stream>>>(srcv, dstv, offsets, cursor, dinv, srcs, wts);

    // ---- fused conversions (x + all weights) ----
    {
        const int tot4 = NN * IND / 4 + CD * IND / 4 + 6 * CD * CD / 4
                       + 2 * (LL * 3 * CD * CD / 4) + OUTD * CD / 4;
        conv_all_kernel<<<(tot4 + 255) / 256, 256, 0, stream>>>(
            x, gcn_w, ggc_w, gru_wih, gru_whh, lin_w,
            x_h, gcn_wt, ggc_h, wih_h, whh_h, lin_wt);
    }

    // ---- all 6 Bc = wih @ ggc^T in one launch ----
    gemm_bc_kernel<<<72, 256, 0, stream>>>(wih_h, ggc_h, Bc);

    const int gmx = (NN + 127) / 128;      // 157
    const int nv4 = (NN * (CD / 4) + 255) / 256;
    const int nfused = ((NN + 63) / 64) * 4;  // 1252
    const int nagg256 = (NN + 7) / 8;      // 8 nodes/block (2/wave)
    const int nagg128 = (NN + 15) / 16;    // 16 nodes/block (4/wave)

    // ---- GCNConv: aggregate x (128ch), then GEMM with fused stage-0 stats ----
    float* sums0  = sums_all;
    float* sumsq0 = sums0 + GG * CD;
    agg_kernel<IND, true><<<nagg128, 256, 0, stream>>>(x_h, offsets, srcs, wts, dinv, ax_h);
    gemm_mfma<true, true, true><<<dim3(gmx, CD / 128), 256, 0, stream>>>(
        ax_h, gcn_wt, gcn_b, nullptr, a_h, NN, CD, IND, batch, sums0, sumsq0);
    gn_apply_kernel<false><<<nv4, 256, 0, stream>>>(a_h, batch, sums0, sumsq0, cntg,
                                                    gn0_w, gn0_ms, gn0_b, h_h);

    // ---- gated blocks (state lives in h_h after each norm) ----
    for (int l = 0; l < LL; ++l) {
        const u16* whh = whh_h + (size_t)l * 3 * CD * CD;
        const float* bih = gru_bih + (size_t)l * 3 * CD;
        const float* bhh = gru_bhh + (size_t)l * 3 * CD;
        float* sums  = sums_all + (size_t)(1 + l) * 2 * GG * CD;
        float* sumsq = sums + GG * CD;
        const u16* Bc0 = Bc + ((size_t)l * 2 + 0) * 3 * CD * CD;
        const u16* Bc1 = Bc + ((size_t)l * 2 + 1) * 3 * CD * CD;

        // i = 0: state h_h -> gmid
        agg_kernel<CD, false><<<nagg256, 256, 0, stream>>>(h_h, offsets, srcs, wts, dinv, a_h);
        fused_gate_gru_kernel<false><<<nfused, 256, 0, stream>>>(
            a_h, h_h, Bc0, whh, bih, bhh, gmid, nullptr, nullptr, nullptr, nullptr);
        // i = 1: state gmid -> (gelu m_h + stats); raw state dead
        agg_kernel<CD, false><<<nagg256, 256, 0, stream>>>(gmid, offsets, srcs, wts, dinv, a_h);
        fused_gate_gru_kernel<true><<<nfused, 256, 0, stream>>>(
            a_h, gmid, Bc1, whh, bih, bhh, nullptr, batch, m_h, sums, sumsq);

        gn_apply_kernel<true><<<nv4, 256, 0, stream>>>(m_h, batch, sums, sumsq, cntg,
                                                       gn_w + l * CD, gn_ms + l * CD, gn_b + l * CD, h_h);
    }

    // ---- final linear on f16 h ----
    gemm_mfma<true, false, false><<<dim3(gmx, OUTD / 128), 256, 0, stream>>>(
        h_h, lin_wt, lin_b, outp, nullptr, NN, OUTD, CD, nullptr, nullptr, nullptr);
}

// Round 21
// 512.170 us; speedup vs baseline: 1.4228x; 1.0333x over previous
//
#include <hip/hip_runtime.h>
#include <math.h>

typedef unsigned short u16;
typedef _Float16 f16;
typedef __attribute__((ext_vector_type(8))) _Float16 f16x8;
typedef __attribute__((ext_vector_type(4))) float f32x4;
typedef __attribute__((ext_vector_type(8))) unsigned short u16x8;

constexpr int NN   = 20000;
constexpr int EE   = 320000;
constexpr int CD   = 256;
constexpr int IND  = 128;
constexpr int OUTD = 128;
constexpr int LL   = 3;
constexpr int GG   = 16;
constexpr float EPSV = 1e-5f;

__device__ __forceinline__ u16 f2h(float f) {
    union { f16 h; u16 u; } v; v.h = (f16)f; return v.u;
}
__device__ __forceinline__ float h2f(u16 u) {
    union { u16 u; f16 h; } v; v.u = u; return (float)v.h;
}
// fast transcendentals via v_exp_f32 / v_rcp_f32 (saturating forms; no overflow)
__device__ __forceinline__ float frcp(float x) { return __builtin_amdgcn_rcpf(x); }
__device__ __forceinline__ float fsig(float x) { return frcp(1.f + __expf(-x)); }
__device__ __forceinline__ float ftanh(float x) {
    float t = __expf(-2.f * fabsf(x));
    float r = (1.f - t) * frcp(1.f + t);
    return copysignf(r, x);
}
__device__ __forceinline__ float fgelu(float x) {
    float u = 0.7978845608028654f * (x + 0.044715f * x * x * x);
    return 0.5f * x * (1.f + ftanh(u));
}

// ---------------------------------------------------------------------------
// CSR build: fused edge histogram + batch histogram
// ---------------------------------------------------------------------------
__global__ void hist_kernel(const int* __restrict__ dst, const int* __restrict__ batch,
                            int* __restrict__ counts, int* __restrict__ cntg) {
    __shared__ int loc[GG];
    if (threadIdx.x < GG) loc[threadIdx.x] = 0;
    __syncthreads();
    int stride = gridDim.x * blockDim.x;
    for (int e = blockIdx.x * blockDim.x + threadIdx.x; e < EE; e += stride)
        atomicAdd(&counts[dst[e]], 1);
    for (int i = blockIdx.x * blockDim.x + threadIdx.x; i < NN; i += stride)
        atomicAdd(&loc[batch[i]], 1);
    __syncthreads();
    if (threadIdx.x < GG) atomicAdd(&cntg[threadIdx.x], loc[threadIdx.x]);
}

__global__ __launch_bounds__(1024) void scan_kernel(const int* __restrict__ counts,
                                                    int* __restrict__ offsets,
                                                    float* __restrict__ dinv) {
    __shared__ int ls[1024];
    int t = threadIdx.x;
    const int CHK = (NN + 1023) / 1024;
    int begin = t * CHK;
    int end   = begin + CHK; if (end > NN) end = NN;
    int s = 0;
    for (int i = begin; i < end && i < NN; ++i) s += counts[i];
    ls[t] = s;
    __syncthreads();
    for (int off = 1; off < 1024; off <<= 1) {
        int v = (t >= off) ? ls[t - off] : 0;
        __syncthreads();
        ls[t] += v;
        __syncthreads();
    }
    int run = ls[t] - s;
    for (int i = begin; i < end && i < NN; ++i) {
        offsets[i] = run;
        int c = counts[i];
        run += c;
        dinv[i] = rsqrtf((float)(c + 1));
    }
    if (t == 1023) offsets[NN] = run;
}

__global__ void fill_kernel(const int* __restrict__ src, const int* __restrict__ dst,
                            const int* __restrict__ offsets, int* __restrict__ cursor,
                            const float* __restrict__ dinv,
                            int* __restrict__ srcs, float* __restrict__ wts) {
    int e = blockIdx.x * blockDim.x + threadIdx.x;
    if (e >= EE) return;
    int d = dst[e];
    int p = atomicAdd(&cursor[d], 1);
    int pos = offsets[d] + p;
    int s = src[e];
    srcs[pos] = s;
    wts[pos]  = dinv[s];
}

// ---------------------------------------------------------------------------
// Fused f32 -> f16 conversion of x + all weights (one launch)
// ---------------------------------------------------------------------------
__global__ void conv_all_kernel(const float* __restrict__ x,   const float* __restrict__ gcn_w,
                                const float* __restrict__ ggc, const float* __restrict__ wih,
                                const float* __restrict__ whh, const float* __restrict__ lin,
                                u16* __restrict__ x_h,  u16* __restrict__ gcn_h,
                                u16* __restrict__ ggc_h, u16* __restrict__ wih_h,
                                u16* __restrict__ whh_h, u16* __restrict__ lin_h) {
    const int b0 = NN * IND / 4;
    const int b1 = b0 + CD * IND / 4;
    const int b2 = b1 + 6 * CD * CD / 4;
    const int b3 = b2 + LL * 3 * CD * CD / 4;
    const int b4 = b3 + LL * 3 * CD * CD / 4;
    const int b5 = b4 + OUTD * CD / 4;
    int i = blockIdx.x * blockDim.x + threadIdx.x;
    if (i >= b5) return;
    const float* src; u16* dst; int base;
    if (i < b0)      { src = x;     dst = x_h;   base = 0;  }
    else if (i < b1) { src = gcn_w; dst = gcn_h; base = b0; }
    else if (i < b2) { src = ggc;   dst = ggc_h; base = b1; }
    else if (i < b3) { src = wih;   dst = wih_h; base = b2; }
    else if (i < b4) { src = whh;   dst = whh_h; base = b3; }
    else             { src = lin;   dst = lin_h; base = b4; }
    int j = i - base;
    float4 v = ((const float4*)src)[j];
    ushort4 o;
    o.x = f2h(v.x); o.y = f2h(v.y); o.z = f2h(v.z); o.w = f2h(v.w);
    ((ushort4*)dst)[j] = o;
}

// ---------------------------------------------------------------------------
// f16 MFMA GEMM tile body: C[M,N] = A[M,K] * B^T (B stored [N,K]) (+bias)
// 128x128 tile, BK=64, 4 waves, global_load_lds w16, XOR-swizzled LDS (T2).
// STATS: also accumulate per-(graph,col) sums/sumsq of the f32 outputs.
// ---------------------------------------------------------------------------
template<bool BIAS, bool OUTH, bool STATS>
__device__ __forceinline__ void gemm_tile(const u16* __restrict__ A,
                                          const u16* __restrict__ B,
                                          const float* __restrict__ bias,
                                          float* __restrict__ Cf,
                                          u16* __restrict__ Ch,
                                          int M, int N, int K,
                                          int bm, int bn,
                                          u16* As, u16* Bs,
                                          const int* __restrict__ batch,
                                          float* __restrict__ sums,
                                          float* __restrict__ sumsq) {
    const int tid  = threadIdx.x;
    const int lane = tid & 63;
    const int wave = tid >> 6;
    const int wr = wave >> 1, wc = wave & 1;

    f32x4 acc[4][4];
    #pragma unroll
    for (int i = 0; i < 4; ++i)
        #pragma unroll
        for (int j = 0; j < 4; ++j) acc[i][j] = (f32x4)0.f;

    const int srow = tid >> 3;                              // 0..31
    const int skc  = ((tid & 7) * 8) ^ ((srow & 7) << 3);   // swizzled source k-offset

    const int fr = lane & 15;
    const int kg = (lane >> 4) * 8;
    const int rsw = (fr & 7) << 3;

    for (int k0 = 0; k0 < K; k0 += 64) {
        #pragma unroll
        for (int it = 0; it < 4; ++it) {
            int row  = srow + it * 32;
            int arow = bm + row; if (arow >= M) arow = M - 1;
            const u16* ga = &A[(size_t)arow * K + k0 + skc];
            const u16* gb = &B[(size_t)(bn + row) * K + k0 + skc];
            __builtin_amdgcn_global_load_lds(
                (const __attribute__((address_space(1))) void*)ga,
                (__attribute__((address_space(3))) void*)((char*)As + it * 4096 + tid * 16),
                16, 0, 0);
            __builtin_amdgcn_global_load_lds(
                (const __attribute__((address_space(1))) void*)gb,
                (__attribute__((address_space(3))) void*)((char*)Bs + it * 4096 + tid * 16),
                16, 0, 0);
        }
        __syncthreads();

        #pragma unroll
        for (int ks = 0; ks < 2; ++ks) {
            const int col = (ks * 32 + kg) ^ rsw;
            f16x8 af[4], bfr[4];
            #pragma unroll
            for (int m2 = 0; m2 < 4; ++m2)
                af[m2] = *(const f16x8*)&As[(wr * 64 + m2 * 16 + fr) * 64 + col];
            #pragma unroll
            for (int n2 = 0; n2 < 4; ++n2)
                bfr[n2] = *(const f16x8*)&Bs[(wc * 64 + n2 * 16 + fr) * 64 + col];
            #pragma unroll
            for (int m2 = 0; m2 < 4; ++m2)
                #pragma unroll
                for (int n2 = 0; n2 < 4; ++n2)
                    acc[m2][n2] = __builtin_amdgcn_mfma_f32_16x16x32_f16(af[m2], bfr[n2], acc[m2][n2], 0, 0, 0);
        }
        __syncthreads();
    }

    const int fq = lane >> 4;
    float bv[4];
    if (BIAS) {
        #pragma unroll
        for (int n2 = 0; n2 < 4; ++n2) bv[n2] = bias[bn + wc * 64 + n2 * 16 + fr];
    }
    #pragma unroll
    for (int m2 = 0; m2 < 4; ++m2) {
        const int rb = bm + wr * 64 + m2 * 16;   // wave-uniform 16-row window
        #pragma unroll
        for (int n2 = 0; n2 < 4; ++n2) {
            int col = bn + wc * 64 + n2 * 16 + fr;
            float gv[4];
            #pragma unroll
            for (int j = 0; j < 4; ++j) {
                gv[j] = 0.f;
                int r = rb + fq * 4 + j;
                if (r < M) {
                    float v = acc[m2][n2][j];
                    if (BIAS) v += bv[n2];
                    if (OUTH) Ch[(size_t)r * N + col] = f2h(v);
                    else      Cf[(size_t)r * N + col] = v;
                    if (STATS) gv[j] = v;
                }
            }
            if (STATS) {
                bool uni = (rb + 15 < M) && (batch[rb] == batch[rb + 15]);
                if (uni) {
                    float s = gv[0] + gv[1] + gv[2] + gv[3];
                    float qq = gv[0]*gv[0] + gv[1]*gv[1] + gv[2]*gv[2] + gv[3]*gv[3];
                    s  += __shfl_xor(s, 16);  s  += __shfl_xor(s, 32);
                    qq += __shfl_xor(qq, 16); qq += __shfl_xor(qq, 32);
                    if (fq == 0) {
                        int gb2 = batch[rb];
                        atomicAdd(&sums [gb2 * CD + col], s);
                        atomicAdd(&sumsq[gb2 * CD + col], qq);
                    }
                } else {
                    int run = -1; float s = 0.f, qq = 0.f;
                    #pragma unroll
                    for (int j = 0; j < 4; ++j) {
                        int r = rb + fq * 4 + j;
                        if (r >= M) break;
                        int gb2 = batch[r];
                        if (gb2 != run) {
                            if (run >= 0) {
                                atomicAdd(&sums [run * CD + col], s);
                                atomicAdd(&sumsq[run * CD + col], qq);
                            }
                            run = gb2; s = 0.f; qq = 0.f;
                        }
                        s += gv[j]; qq += gv[j] * gv[j];
                    }
                    if (run >= 0) {
                        atomicAdd(&sums [run * CD + col], s);
                        atomicAdd(&sumsq[run * CD + col], qq);
                    }
                }
            }
        }
    }
}

template<bool BIAS, bool OUTH, bool STATS>
__global__ __launch_bounds__(256) void gemm_mfma(const u16* __restrict__ A,
                                                 const u16* __restrict__ B,
                                                 const float* __restrict__ bias,
                                                 float* __restrict__ Cf,
                                                 u16* __restrict__ Ch,
                                                 int M, int N, int K,
                                                 const int* __restrict__ batch,
                                                 float* __restrict__ sums,
                                                 float* __restrict__ sumsq) {
    __shared__ u16 As[128 * 64];
    __shared__ u16 Bs[128 * 64];
    gemm_tile<BIAS, OUTH, STATS>(A, B, bias, Cf, Ch, M, N, K,
                                 blockIdx.x * 128, blockIdx.y * 128, As, Bs,
                                 batch, sums, sumsq);
}

// All 6 Bc = wih_l @ ggc[l,i]^T  (768x256 each) in ONE launch: 72 blocks
__global__ __launch_bounds__(256) void gemm_bc_kernel(const u16* __restrict__ wih_h,
                                                      const u16* __restrict__ ggc_h,
                                                      u16* __restrict__ Bc) {
    __shared__ u16 As[128 * 64];
    __shared__ u16 Bs[128 * 64];
    int b = blockIdx.x;            // 0..71
    int mat = b / 12, rem = b % 12;
    int bx = rem % 6, by = rem / 6;
    gemm_tile<false, true, false>(wih_h + (size_t)(mat >> 1) * 3 * CD * CD,
                                  ggc_h + (size_t)mat * CD * CD,
                                  nullptr, nullptr,
                                  Bc + (size_t)mat * 3 * CD * CD,
                                  3 * CD, CD, CD, bx * 128, by * 128, As, Bs,
                                  nullptr, nullptr, nullptr);
}

// ---------------------------------------------------------------------------
// FUSED gate-GEMM + GRU (v4 structure) + optional STATS epilogue.
// K-loop ROTATED so the final quarter is k0 == jb: after the loop Ag0 still
// holds g0[rows][jb..jb+63] -- the epilogue reads ho from LDS (zero register
// liveness cost) instead of 16 scattered 2B global loads per thread.
// ---------------------------------------------------------------------------
template<bool STATS>
__global__ __launch_bounds__(256) void fused_gate_gru_kernel(
        const u16* __restrict__ ag,    // agg(g0) [NN][256]
        const u16* __restrict__ g0,    // current state [NN][256]
        const u16* __restrict__ Bc,    // combined wih@W^T [768][256]
        const u16* __restrict__ whh,   // [768][256]
        const float* __restrict__ bih, // [768]
        const float* __restrict__ bhh, // [768]
        u16* __restrict__ g1,          // new state out (!STATS)
        const int* __restrict__ batch, // [NN] (STATS)
        u16* __restrict__ mout,        // gelu out (STATS)
        float* __restrict__ sums,      // [GG][CD] (STATS)
        float* __restrict__ sumsq) {   // [GG][CD] (STATS)
    __shared__ u16 S[32768];           // 64 KB
    u16* Aag = S;                      // 64x64
    u16* Ag0 = S + 4096;               // 64x64
    u16* SBc = S + 8192;               // 192x64
    u16* SWh = S + 20480;              // 192x64

    const int nwg = gridDim.x;         // 1252
    const int q = nwg >> 3, r = nwg & 7;
    int xcd = blockIdx.x & 7, idx = blockIdx.x >> 3;
    int nid = (xcd < r ? xcd * (q + 1) : r * (q + 1) + (xcd - r) * q) + idx;
    const int bm = (nid >> 2) * 64;    // row base
    const int jb = (nid & 3) * 64;     // gru-col base

    const int tid  = threadIdx.x;
    const int lane = tid & 63;
    const int wave = tid >> 6;         // 0..3
    const int wrow = wave >> 1;
    const int wcol = wave & 1;
    const int fr = lane & 15;
    const int fq = lane >> 4;
    const int kg = fq * 8;
    const int rsw = (fr & 7) << 3;

    const int srow = tid >> 3;                              // 0..31
    const int skc  = ((tid & 7) * 8) ^ ((srow & 7) << 3);   // swizzled src k-off

    f32x4 acc[6][2][2];
    #pragma unroll
    for (int g = 0; g < 6; ++g)
        #pragma unroll
        for (int m = 0; m < 2; ++m)
            #pragma unroll
            for (int n = 0; n < 2; ++n) acc[g][m][n] = (f32x4)0.f;

    // rotated K order: jb+64, jb+128, jb+192, jb (mod 256) -> last quarter = jb
    #pragma unroll
    for (int kk = 1; kk <= 4; ++kk) {
        const int k0 = (jb + kk * 64) & 255;
        #pragma unroll
        for (int it = 0; it < 2; ++it) {
            int arow = bm + it * 32 + srow; if (arow >= NN) arow = NN - 1;
            __builtin_amdgcn_global_load_lds(
                (const __attribute__((address_space(1))) void*)&ag[(size_t)arow * CD + k0 + skc],
                (__attribute__((address_space(3))) void*)((char*)Aag + it * 4096 + tid * 16),
                16, 0, 0);
            __builtin_amdgcn_global_load_lds(
                (const __attribute__((address_space(1))) void*)&g0[(size_t)arow * CD + k0 + skc],
                (__attribute__((address_space(3))) void*)((char*)Ag0 + it * 4096 + tid * 16),
                16, 0, 0);
        }
        #pragma unroll
        for (int p = 0; p < 3; ++p) {
            #pragma unroll
            for (int hf = 0; hf < 2; ++hf) {
                int grow = p * 256 + jb + hf * 32 + srow;
                __builtin_amdgcn_global_load_lds(
                    (const __attribute__((address_space(1))) void*)&Bc[(size_t)grow * CD + k0 + skc],
                    (__attribute__((address_space(3))) void*)((char*)SBc + p * 8192 + hf * 4096 + tid * 16),
                    16, 0, 0);
                __builtin_amdgcn_global_load_lds(
                    (const __attribute__((address_space(1))) void*)&whh[(size_t)grow * CD + k0 + skc],
                    (__attribute__((address_space(3))) void*)((char*)SWh + p * 8192 + hf * 4096 + tid * 16),
                    16, 0, 0);
            }
        }
        __syncthreads();

        #pragma unroll
        for (int ks = 0; ks < 2; ++ks) {
            const int col = (ks * 32 + kg) ^ rsw;
            f16x8 aa[2], gg[2];
            #pragma unroll
            for (int m = 0; m < 2; ++m) {
                int arl = (wrow * 32 + m * 16 + fr) * 64 + col;
                aa[m] = *(const f16x8*)&Aag[arl];
                gg[m] = *(const f16x8*)&Ag0[arl];
            }
            #pragma unroll
            for (int p = 0; p < 3; ++p) {
                #pragma unroll
                for (int n = 0; n < 2; ++n) {
                    int brl = p * 4096 + (wcol * 32 + n * 16 + fr) * 64 + col;
                    f16x8 bc = *(const f16x8*)&SBc[brl];
                    f16x8 bw = *(const f16x8*)&SWh[brl];
                    #pragma unroll
                    for (int m = 0; m < 2; ++m) {
                        acc[p][m][n]     = __builtin_amdgcn_mfma_f32_16x16x32_f16(aa[m], bc, acc[p][m][n], 0, 0, 0);
                        acc[3 + p][m][n] = __builtin_amdgcn_mfma_f32_16x16x32_f16(gg[m], bw, acc[3 + p][m][n], 0, 0, 0);
                    }
                }
            }
        }
        if (kk < 4) __syncthreads();   // after last quarter keep Ag0 intact
    }

    float bI[3][2], bH[3][2];
    #pragma unroll
    for (int p = 0; p < 3; ++p)
        #pragma unroll
        for (int n = 0; n < 2; ++n) {
            int gc = p * 256 + jb + wcol * 32 + n * 16 + fr;
            bI[p][n] = bih[gc];
            bH[p][n] = bhh[gc];
        }

    #pragma unroll
    for (int m = 0; m < 2; ++m) {
        const int rb = bm + wrow * 32 + m * 16;   // wave-uniform window
        #pragma unroll
        for (int n = 0; n < 2; ++n) {
            int col = jb + wcol * 32 + n * 16 + fr;
            const int colq = wcol * 32 + n * 16 + fr;   // col within the jb quarter
            float gv[4];
            #pragma unroll
            for (int jj = 0; jj < 4; ++jj) {
                gv[jj] = 0.f;
                int row = rb + fq * 4 + jj;
                if (row >= NN) continue;
                float Ir = acc[0][m][n][jj] + bI[0][n];
                float Iz = acc[1][m][n][jj] + bI[1][n];
                float In = acc[2][m][n][jj] + bI[2][n];
                float Hr = acc[3][m][n][jj] + bH[0][n];
                float Hz = acc[4][m][n][jj] + bH[1][n];
                float Hn = acc[5][m][n][jj] + bH[2][n];
                float rr = fsig(Ir + Hr);
                float zz = fsig(Iz + Hz);
                float nv = ftanh(In + rr * Hn);
                const int rloc = wrow * 32 + m * 16 + fq * 4 + jj;
                float ho = h2f(Ag0[rloc * 64 + (colq ^ ((rloc & 7) << 3))]);
                float res = (1.f - zz) * nv + zz * ho;
                if (!STATS) {
                    g1[(size_t)row * CD + col] = f2h(res);
                } else {
                    float val = fgelu(res);
                    mout[(size_t)row * CD + col] = f2h(val);
                    gv[jj] = val;
                }
            }
            if (STATS) {
                bool uni = (rb + 15 < NN) && (batch[rb] == batch[rb + 15]);
                if (uni) {
                    float s = gv[0] + gv[1] + gv[2] + gv[3];
                    float qq = gv[0]*gv[0] + gv[1]*gv[1] + gv[2]*gv[2] + gv[3]*gv[3];
                    s  += __shfl_xor(s, 16);  s  += __shfl_xor(s, 32);
                    qq += __shfl_xor(qq, 16); qq += __shfl_xor(qq, 32);
                    if (fq == 0) {
                        int gb2 = batch[rb];
                        atomicAdd(&sums [gb2 * CD + col], s);
                        atomicAdd(&sumsq[gb2 * CD + col], qq);
                    }
                } else {
                    int run = -1; float s = 0.f, qq = 0.f;
                    #pragma unroll
                    for (int jj = 0; jj < 4; ++jj) {
                        int row = rb + fq * 4 + jj;
                        if (row >= NN) break;
                        int gb2 = batch[row];
                        if (gb2 != run) {
                            if (run >= 0) {
                                atomicAdd(&sums [run * CD + col], s);
                                atomicAdd(&sumsq[run * CD + col], qq);
                            }
                            run = gb2; s = 0.f; qq = 0.f;
                        }
                        s += gv[jj]; qq += gv[jj] * gv[jj];
                    }
                    if (run >= 0) {
                        atomicAdd(&sums [run * CD + col], s);
                        atomicAdd(&sumsq[run * CD + col], qq);
                    }
                }
            }
        }
    }
}

// ---------------------------------------------------------------------------
// Edge aggregation: WAVE-per-node, register-only, 16B/lane (u16x8).
// ---------------------------------------------------------------------------
template<int CHN, bool GCN>
__global__ __launch_bounds__(256) void agg_kernel(const u16* __restrict__ feat,
                                                  const int* __restrict__ offsets,
                                                  const int* __restrict__ srcs,
                                                  const float* __restrict__ wts,
                                                  const float* __restrict__ dinv,
                                                  u16* __restrict__ outp) {
    constexpr int LPN = CHN / 8;       // lanes per node
    constexpr int NPW = 64 / LPN;      // nodes per wave
    constexpr int NPB = 4 * NPW;       // nodes per block
    const int lane = threadIdx.x & 63;
    const int wave = threadIdx.x >> 6;
    const int sub  = lane / LPN;
    const int ln   = lane % LPN;
    const int v = blockIdx.x * NPB + wave * NPW + sub;
    if (v >= NN) return;

    const int o0 = offsets[v], o1 = offsets[v + 1];
    float a[8];
    #pragma unroll
    for (int t = 0; t < 8; ++t) a[t] = 0.f;
    int o = o0;
    for (; o + 4 <= o1; o += 4) {
        int s0 = srcs[o], s1 = srcs[o + 1], s2 = srcs[o + 2], s3 = srcs[o + 3];
        u16x8 m0 = *(const u16x8*)&feat[(size_t)s0 * CHN + ln * 8];
        u16x8 m1 = *(const u16x8*)&feat[(size_t)s1 * CHN + ln * 8];
        u16x8 m2 = *(const u16x8*)&feat[(size_t)s2 * CHN + ln * 8];
        u16x8 m3 = *(const u16x8*)&feat[(size_t)s3 * CHN + ln * 8];
        float w0 = GCN ? wts[o]     : 1.f;
        float w1 = GCN ? wts[o + 1] : 1.f;
        float w2 = GCN ? wts[o + 2] : 1.f;
        float w3 = GCN ? wts[o + 3] : 1.f;
        #pragma unroll
        for (int t = 0; t < 8; ++t)
            a[t] += w0 * h2f(m0[t]) + w1 * h2f(m1[t]) + w2 * h2f(m2[t]) + w3 * h2f(m3[t]);
    }
    for (; o < o1; ++o) {
        int s = srcs[o];
        float w = GCN ? wts[o] : 1.f;
        u16x8 mv = *(const u16x8*)&feat[(size_t)s * CHN + ln * 8];
        #pragma unroll
        for (int t = 0; t < 8; ++t) a[t] += w * h2f(mv[t]);
    }
    if (GCN) {
        float dv = dinv[v];
        u16x8 sv = *(const u16x8*)&feat[(size_t)v * CHN + ln * 8];
        #pragma unroll
        for (int t = 0; t < 8; ++t) a[t] = dv * a[t] + dv * dv * h2f(sv[t]);
    }
    u16x8 ov;
    #pragma unroll
    for (int t = 0; t < 8; ++t) ov[t] = f2h(a[t]);
    *(u16x8*)&outp[(size_t)v * CHN + ln * 8] = ov;
}

// ---------------------------------------------------------------------------
// GN apply with inline finalize; writes h_h only (post-norm state == residual).
// ---------------------------------------------------------------------------
template<bool RES>
__global__ void gn_apply_kernel(const u16* __restrict__ x,
                                const int* __restrict__ batch,
                                const float* __restrict__ sums,
                                const float* __restrict__ sumsq,
                                const int* __restrict__ cntg,
                                const float* __restrict__ w,
                                const float* __restrict__ ms,
                                const float* __restrict__ bvec,
                                u16* __restrict__ h_h) {
    int i = blockIdx.x * blockDim.x + threadIdx.x;   // over NN*64
    if (i >= NN * (CD / 4)) return;
    int v = i >> 6, c4 = (i & 63) << 2;
    int gb = batch[v];
    size_t idx = (size_t)v * CD + c4;
    ushort4 xv = *(const ushort4*)&x[idx];
    float4 sm = *(const float4*)&sums[gb * CD + c4];
    float4 sq = *(const float4*)&sumsq[gb * CD + c4];
    float4 wv = *(const float4*)&w[c4];
    float4 mv = *(const float4*)&ms[c4];
    float4 bb = *(const float4*)&bvec[c4];
    float rc = 1.0f / fmaxf((float)cntg[gb], 1.0f);
    float4 val;
    #pragma unroll
    for (int t = 0; t < 4; ++t) {
        float mean = (&sm.x)[t] * rc;
        float ex2  = (&sq.x)[t] * rc;
        float msm  = (&mv.x)[t] * mean;
        float var  = ex2 - 2.f * msm * mean + msm * msm;
        float scale = (&wv.x)[t] * rsqrtf(var + EPSV);
        (&val.x)[t] = (h2f((&xv.x)[t]) - msm) * scale + (&bb.x)[t];
    }
    if (RES) {
        ushort4 hv = *(const ushort4*)&h_h[idx];
        val.x += h2f(hv.x); val.y += h2f(hv.y); val.z += h2f(hv.z); val.w += h2f(hv.w);
    }
    ushort4 ov; ov.x = f2h(val.x); ov.y = f2h(val.y); ov.z = f2h(val.z); ov.w = f2h(val.w);
    *(ushort4*)&h_h[idx] = ov;
}

// ---------------------------------------------------------------------------
// Host
// ---------------------------------------------------------------------------
extern "C" void kernel_launch(void* const* d_in, const int* in_sizes, int n_in,
                              void* d_out, int out_size, void* d_ws, size_t ws_size,
                              hipStream_t stream) {
    const float* x      = (const float*)d_in[0];
    const int*   ei     = (const int*)d_in[1];
    const int*   batch  = (const int*)d_in[2];
    const float* gcn_w  = (const float*)d_in[3];
    const float* gcn_b  = (const float*)d_in[4];
    const float* gn0_w  = (const float*)d_in[5];
    const float* gn0_b  = (const float*)d_in[6];
    const float* gn0_ms = (const float*)d_in[7];
    const float* ggc_w  = (const float*)d_in[8];
    const float* gru_wih = (const float*)d_in[9];
    const float* gru_whh = (const float*)d_in[10];
    const float* gru_bih = (const float*)d_in[11];
    const float* gru_bhh = (const float*)d_in[12];
    const float* gn_w   = (const float*)d_in[13];
    const float* gn_b   = (const float*)d_in[14];
    const float* gn_ms  = (const float*)d_in[15];
    const float* lin_w  = (const float*)d_in[16];
    const float* lin_b  = (const float*)d_in[17];
    float* outp = (float*)d_out;

    const int* srcv = ei;
    const int* dstv = ei + EE;

    char* base = (char*)d_ws;
    size_t off = 0;
    auto alloc = [&](size_t bytes) -> void* {
        void* p = base + off;
        off = (off + bytes + 255) & ~(size_t)255;
        return p;
    };

    // ---- zeroed-at-start region ----
    int*   counts   = (int*)alloc(NN * 4);
    int*   cursor   = (int*)alloc(NN * 4);
    int*   cntg     = (int*)alloc(GG * 4);
    float* sums_all = (float*)alloc((size_t)4 * 2 * GG * CD * 4);  // 4 stages x (sums,sumsq)
    size_t zero_end = off;

    int*   offsets = (int*)alloc((NN + 1) * 4);
    int*   srcs    = (int*)alloc((size_t)EE * 4);
    float* wts     = (float*)alloc((size_t)EE * 4);
    float* dinv    = (float*)alloc(NN * 4);
    // f16 weights
    u16* gcn_wt = (u16*)alloc((size_t)CD * IND * 2);
    u16* ggc_h  = (u16*)alloc((size_t)6 * CD * CD * 2);
    u16* wih_h  = (u16*)alloc((size_t)LL * 3 * CD * CD * 2);
    u16* whh_h  = (u16*)alloc((size_t)LL * 3 * CD * CD * 2);
    u16* lin_wt = (u16*)alloc((size_t)OUTD * CD * 2);
    u16* Bc     = (u16*)alloc((size_t)6 * 3 * CD * CD * 2);
    // activations (all f16)
    u16* x_h  = (u16*)alloc((size_t)NN * IND * 2);
    u16* ax_h = (u16*)alloc((size_t)NN * IND * 2);
    u16* gmid = (u16*)alloc((size_t)NN * CD * 2);
    u16* h_h  = (u16*)alloc((size_t)NN * CD * 2);
    u16* m_h  = (u16*)alloc((size_t)NN * CD * 2);
    u16* a_h  = (u16*)alloc((size_t)NN * CD * 2);

    // ---- CSR build + per-graph counts ----
    hipMemsetAsync(counts, 0, zero_end, stream);
    hist_kernel<<<512, 256, 0, stream>>>(dstv, batch, counts, cntg);
    scan_kernel<<<1, 1024, 0, stream>>>(counts, offsets, dinv);
    fill_kernel<<<(EE + 255) / 256, 256, 0, stream>>>(srcv, dstv, offsets, cursor, dinv, srcs, wts);

    // ---- fused conversions (x + all weights) ----
    {
        const int tot4 = NN * IND / 4 + CD * IND / 4 + 6 * CD * CD / 4
                       + 2 * (LL * 3 * CD * CD / 4) + OUTD * CD / 4;
        conv_all_kernel<<<(tot4 + 255) / 256, 256, 0, stream>>>(
            x, gcn_w, ggc_w, gru_wih, gru_whh, lin_w,
            x_h, gcn_wt, ggc_h, wih_h, whh_h, lin_wt);
    }

    // ---- all 6 Bc = wih @ ggc^T in one launch ----
    gemm_bc_kernel<<<72, 256, 0, stream>>>(wih_h, ggc_h, Bc);

    const int gmx = (NN + 127) / 128;      // 157
    const int nv4 = (NN * (CD / 4) + 255) / 256;
    const int nfused = ((NN + 63) / 64) * 4;  // 1252
    const int nagg256 = (NN + 7) / 8;      // 8 nodes/block (2/wave)
    const int nagg128 = (NN + 15) / 16;    // 16 nodes/block (4/wave)

    // ---- GCNConv: aggregate x (128ch), then GEMM with fused stage-0 stats ----
    float* sums0  = sums_all;
    float* sumsq0 = sums0 + GG * CD;
    agg_kernel<IND, true><<<nagg128, 256, 0, stream>>>(x_h, offsets, srcs, wts, dinv, ax_h);
    gemm_mfma<true, true, true><<<dim3(gmx, CD / 128), 256, 0, stream>>>(
        ax_h, gcn_wt, gcn_b, nullptr, a_h, NN, CD, IND, batch, sums0, sumsq0);
    gn_apply_kernel<false><<<nv4, 256, 0, stream>>>(a_h, batch, sums0, sumsq0, cntg,
                                                    gn0_w, gn0_ms, gn0_b, h_h);

    // ---- gated blocks (state lives in h_h after each norm) ----
    for (int l = 0; l < LL; ++l) {
        const u16* whh = whh_h + (size_t)l * 3 * CD * CD;
        const float* bih = gru_bih + (size_t)l * 3 * CD;
        const float* bhh = gru_bhh + (size_t)l * 3 * CD;
        float* sums  = sums_all + (size_t)(1 + l) * 2 * GG * CD;
        float* sumsq = sums + GG * CD;
        const u16* Bc0 = Bc + ((size_t)l * 2 + 0) * 3 * CD * CD;
        const u16* Bc1 = Bc + ((size_t)l * 2 + 1) * 3 * CD * CD;

        // i = 0: state h_h -> gmid
        agg_kernel<CD, false><<<nagg256, 256, 0, stream>>>(h_h, offsets, srcs, wts, dinv, a_h);
        fused_gate_gru_kernel<false><<<nfused, 256, 0, stream>>>(
            a_h, h_h, Bc0, whh, bih, bhh, gmid, nullptr, nullptr, nullptr, nullptr);
        // i = 1: state gmid -> (gelu m_h + stats); raw state dead
        agg_kernel<CD, false><<<nagg256, 256, 0, stream>>>(gmid, offsets, srcs, wts, dinv, a_h);
        fused_gate_gru_kernel<true><<<nfused, 256, 0, stream>>>(
            a_h, gmid, Bc1, whh, bih, bhh, nullptr, batch, m_h, sums, sumsq);

        gn_apply_kernel<true><<<nv4, 256, 0, stream>>>(m_h, batch, sums, sumsq, cntg,
                                                       gn_w + l * CD, gn_ms + l * CD, gn_b + l * CD, h_h);
    }

    // ---- final linear on f16 h ----
    gemm_mfma<true, false, false><<<dim3(gmx, OUTD / 128), 256, 0, stream>>>(
        h_h, lin_wt, lin_b, outp, nullptr, NN, OUTD, CD, nullptr, nullptr, nullptr);
}